// Round 1
// baseline (3658.973 us; speedup 1.0000x reference)
//
#include <hip/hip_runtime.h>
#include <math.h>

#define HID 128
#define EPB 16          // edges per block in edge MLP
#define RS  272         // padded repr stride (268 rounded to x4, float4-aligned)

__global__ void deg_kernel(const int* __restrict__ dst, float* __restrict__ deg, int E) {
    int e = blockIdx.x * blockDim.x + threadIdx.x;
    if (e < E) atomicAdd(&deg[dst[e]], 1.0f);
}

__global__ void node_proj_kernel(const float* __restrict__ x, const float* __restrict__ W,
                                 const float* __restrict__ b, float* __restrict__ h, int N) {
    int i = blockIdx.x * blockDim.x + threadIdx.x;
    if (i >= N * HID) return;
    int n = i >> 7, f = i & 127;
    float acc = b[f];
#pragma unroll
    for (int k = 0; k < 5; k++) acc = fmaf(x[n * 5 + k], W[k * HID + f], acc);
    h[i] = acc;
}

__global__ void scatter_kernel(const float* __restrict__ h, const int* __restrict__ src,
                               const int* __restrict__ dst, float* __restrict__ agg, int E) {
    int i = blockIdx.x * blockDim.x + threadIdx.x;
    if (i >= E * HID) return;                 // E*HID = 102.4M < 2^31
    int e = i >> 7, f = i & 127;
    atomicAdd(&agg[dst[e] * HID + f], h[src[e] * HID + f]);
}

// agg buffer is read (as aggregation input) and overwritten (as new h) per node row;
// each block only touches its own 4 rows, reads land in LDS before writes -> safe.
__global__ __launch_bounds__(128) void sage_kernel(
    float* __restrict__ aggio, const float* __restrict__ hin,
    const float* __restrict__ deg,
    const float* __restrict__ Wl, const float* __restrict__ bl,
    const float* __restrict__ Wr, const float* __restrict__ g,
    const float* __restrict__ bet, int N) {
    const int t = threadIdx.x;
    const int nodeBase = blockIdx.x * 4;
    __shared__ float s_mean[4][HID];
    __shared__ float s_h[4][HID];
    __shared__ float s_red[4][2];

#pragma unroll
    for (int n = 0; n < 4; n++) {
        int node = nodeBase + n;
        int cn = node < N ? node : N - 1;
        float d = deg[cn];
        float inv = d > 0.f ? 1.f / d : 0.f;
        s_h[n][t] = hin[cn * HID + t];
        s_mean[n][t] = aggio[cn * HID + t] * inv;
    }
    __syncthreads();

    float acc[4];
    float blf = bl[t];
#pragma unroll
    for (int n = 0; n < 4; n++) acc[n] = blf;
    for (int k = 0; k < HID; k++) {
        float wl = Wl[k * HID + t];
        float wr = Wr[k * HID + t];
#pragma unroll
        for (int n = 0; n < 4; n++)
            acc[n] = fmaf(s_mean[n][k], wl, fmaf(s_h[n][k], wr, acc[n]));
    }

    // LayerNorm over the 128 features (2 waves per block)
    int lane = t & 63, wid = t >> 6;
#pragma unroll
    for (int n = 0; n < 4; n++) {
        float v = acc[n];
        for (int o = 32; o > 0; o >>= 1) v += __shfl_down(v, o);
        if (lane == 0) s_red[n][wid] = v;
    }
    __syncthreads();
    float mu[4];
#pragma unroll
    for (int n = 0; n < 4; n++) mu[n] = (s_red[n][0] + s_red[n][1]) * (1.f / 128.f);
    __syncthreads();
#pragma unroll
    for (int n = 0; n < 4; n++) {
        float c = acc[n] - mu[n];
        float v = c * c;
        for (int o = 32; o > 0; o >>= 1) v += __shfl_down(v, o);
        if (lane == 0) s_red[n][wid] = v;
    }
    __syncthreads();
    float gf = g[t], bf = bet[t];
#pragma unroll
    for (int n = 0; n < 4; n++) {
        int node = nodeBase + n;
        if (node < N) {
            float var = (s_red[n][0] + s_red[n][1]) * (1.f / 128.f);
            float rstd = rsqrtf(var + 1e-5f);
            float val = (acc[n] - mu[n]) * rstd * gf + bf;
            aggio[node * HID + t] = fmaxf(val, 0.f);
        }
    }
}

__global__ __launch_bounds__(128) void edge_mlp_kernel(
    const float* __restrict__ h, const int* __restrict__ src, const int* __restrict__ dst,
    const float* __restrict__ eattr,
    const float* __restrict__ W1, const float* __restrict__ b1,
    const float* __restrict__ W2, const float* __restrict__ b2,
    const float* __restrict__ W3, const float* __restrict__ b3,
    float* __restrict__ out, int E) {
    const int t = threadIdx.x;
    const int eBase = blockIdx.x * EPB;
    __shared__ __align__(16) float s_repr[EPB * RS];
    __shared__ __align__(16) float s_z1[EPB * HID];
    __shared__ float s_z2[EPB * 65];
    __shared__ int s_src[EPB], s_dst[EPB];

    if (t < EPB) {
        int e = eBase + t;
        int ce = e < E ? e : 0;
        s_src[t] = src[ce];
        s_dst[t] = dst[ce];
    }
    __syncthreads();

    // stage [h_src | h_dst | edge_attr] for 16 edges
    for (int j = t; j < EPB * 268; j += 128) {
        int eo = j / 268, c = j - eo * 268;
        float v;
        if (c < 128)      v = h[s_src[eo] * HID + c];
        else if (c < 256) v = h[s_dst[eo] * HID + (c - 128)];
        else {
            int e = eBase + eo;
            v = (e < E) ? eattr[e * 12 + (c - 256)] : 0.f;
        }
        s_repr[eo * RS + c] = v;
    }
    __syncthreads();

    // layer 1: 268 -> 128, thread t owns output feature t for all 16 edges
    float acc[EPB];
    float b1f = b1[t];
#pragma unroll
    for (int eo = 0; eo < EPB; eo++) acc[eo] = b1f;
    for (int k = 0; k < 268; k += 4) {   // 268 % 4 == 0
        float4 w;
        w.x = W1[(k + 0) * HID + t];
        w.y = W1[(k + 1) * HID + t];
        w.z = W1[(k + 2) * HID + t];
        w.w = W1[(k + 3) * HID + t];
#pragma unroll
        for (int eo = 0; eo < EPB; eo++) {
            const float4 r = *(const float4*)&s_repr[eo * RS + k];
            acc[eo] = fmaf(r.x, w.x, acc[eo]);
            acc[eo] = fmaf(r.y, w.y, acc[eo]);
            acc[eo] = fmaf(r.z, w.z, acc[eo]);
            acc[eo] = fmaf(r.w, w.w, acc[eo]);
        }
    }
#pragma unroll
    for (int eo = 0; eo < EPB; eo++) s_z1[eo * HID + t] = fmaxf(acc[eo], 0.f);
    __syncthreads();

    // layer 2: 128 -> 64, two half-waves each take 8 edges
    const int f2 = t & 63, grp = t >> 6;
    float acc2[8];
    float b2f = b2[f2];
#pragma unroll
    for (int i = 0; i < 8; i++) acc2[i] = b2f;
    for (int k = 0; k < HID; k += 4) {
        float4 w;
        w.x = W2[(k + 0) * 64 + f2];
        w.y = W2[(k + 1) * 64 + f2];
        w.z = W2[(k + 2) * 64 + f2];
        w.w = W2[(k + 3) * 64 + f2];
#pragma unroll
        for (int i = 0; i < 8; i++) {
            const float4 z = *(const float4*)&s_z1[(grp * 8 + i) * HID + k];
            acc2[i] = fmaf(z.x, w.x, acc2[i]);
            acc2[i] = fmaf(z.y, w.y, acc2[i]);
            acc2[i] = fmaf(z.z, w.z, acc2[i]);
            acc2[i] = fmaf(z.w, w.w, acc2[i]);
        }
    }
#pragma unroll
    for (int i = 0; i < 8; i++) s_z2[(grp * 8 + i) * 65 + f2] = fmaxf(acc2[i], 0.f);
    __syncthreads();

    // layer 3 + softplus: one thread per edge (padded stride 65 -> conflict-free)
    if (t < EPB) {
        float a3 = b3[0];
        for (int k = 0; k < 64; k++) a3 = fmaf(s_z2[t * 65 + k], W3[k], a3);
        int e = eBase + t;
        if (e < E) out[e] = fmaxf(a3, 0.f) + log1pf(expf(-fabsf(a3)));
    }
}

extern "C" void kernel_launch(void* const* d_in, const int* in_sizes, int n_in,
                              void* d_out, int out_size, void* d_ws, size_t ws_size,
                              hipStream_t stream) {
    const float* x       = (const float*)d_in[0];
    const int*   ei      = (const int*)d_in[1];
    const float* eattr   = (const float*)d_in[2];
    const float* node_W  = (const float*)d_in[3];
    const float* node_b  = (const float*)d_in[4];
    const float* sage_Wl = (const float*)d_in[5];
    const float* sage_bl = (const float*)d_in[6];
    const float* sage_Wr = (const float*)d_in[7];
    const float* ln_g    = (const float*)d_in[8];
    const float* ln_b    = (const float*)d_in[9];
    const float* W1 = (const float*)d_in[10];
    const float* b1 = (const float*)d_in[11];
    const float* W2 = (const float*)d_in[12];
    const float* b2 = (const float*)d_in[13];
    const float* W3 = (const float*)d_in[14];
    const float* b3 = (const float*)d_in[15];
    float* out = (float*)d_out;

    const int N = in_sizes[0] / 5;
    const int E = in_sizes[1] / 2;
    const int* src  = ei;
    const int* dstp = ei + E;

    size_t hbytes = (size_t)N * HID * sizeof(float);
    char* ws = (char*)d_ws;
    float* bufA = (float*)ws;
    float* bufB = (float*)(ws + hbytes);
    float* deg  = (float*)(ws + 2 * hbytes);

    hipMemsetAsync(deg, 0, (size_t)N * sizeof(float), stream);
    deg_kernel<<<(E + 255) / 256, 256, 0, stream>>>(dstp, deg, E);
    node_proj_kernel<<<(N * HID + 255) / 256, 256, 0, stream>>>(x, node_W, node_b, bufA, N);

    float* hcur = bufA;
    float* other = bufB;
    for (int l = 0; l < 3; l++) {
        hipMemsetAsync(other, 0, hbytes, stream);
        int total = E * HID;
        scatter_kernel<<<(total + 255) / 256, 256, 0, stream>>>(hcur, src, dstp, other, E);
        sage_kernel<<<(N + 3) / 4, 128, 0, stream>>>(
            other, hcur, deg,
            sage_Wl + (size_t)l * HID * HID, sage_bl + (size_t)l * HID,
            sage_Wr + (size_t)l * HID * HID, ln_g + (size_t)l * HID,
            ln_b + (size_t)l * HID, N);
        float* tmp = hcur; hcur = other; other = tmp;  // new h lives in `other`'s buffer
    }

    edge_mlp_kernel<<<(E + EPB - 1) / EPB, 128, 0, stream>>>(
        hcur, src, dstp, eattr, W1, b1, W2, b2, W3, b3, out, E);
}

// Round 2
// 2150.260 us; speedup vs baseline: 1.7016x; 1.7016x over previous
//
#include <hip/hip_runtime.h>
#include <math.h>

#define HID 128
#define ET  64          // edges per block (edge MLP)
#define K1  288         // padded K for layer 1 (268 -> 9*32)
#define AS  296         // A-tile LDS row stride in bf16 (592 B = 148 dw; 20*m%32 -> 2-way, free)
#define Z1S 136         // z1 LDS stride in bf16 (272 B = 68 dw; 4*m%32 -> 2-way, free)

typedef __attribute__((ext_vector_type(8))) short short8;   // 8 bf16 = 4 VGPRs
typedef __attribute__((ext_vector_type(4))) float floatx4;  // MFMA accumulator

static __device__ __forceinline__ unsigned short f2bf(float v) {
    unsigned u = __float_as_uint(v);
    u += 0x7fffu + ((u >> 16) & 1u);   // round-to-nearest-even
    return (unsigned short)(u >> 16);
}

__global__ void deg_kernel(const int* __restrict__ dst, float* __restrict__ deg, int E) {
    int e = blockIdx.x * blockDim.x + threadIdx.x;
    if (e < E) atomicAdd(&deg[dst[e]], 1.0f);
}

__global__ void node_proj_kernel(const float* __restrict__ x, const float* __restrict__ W,
                                 const float* __restrict__ b, float* __restrict__ h, int N) {
    int i = blockIdx.x * blockDim.x + threadIdx.x;
    if (i >= N * HID) return;
    int n = i >> 7, f = i & 127;
    float acc = b[f];
#pragma unroll
    for (int k = 0; k < 5; k++) acc = fmaf(x[n * 5 + k], W[k * HID + f], acc);
    h[i] = acc;
}

__global__ void scatter_kernel(const float* __restrict__ h, const int* __restrict__ src,
                               const int* __restrict__ dst, float* __restrict__ agg, int E) {
    int i = blockIdx.x * blockDim.x + threadIdx.x;
    if (i >= E * HID) return;
    int e = i >> 7, f = i & 127;
    atomicAdd(&agg[dst[e] * HID + f], h[src[e] * HID + f]);
}

__global__ __launch_bounds__(128) void sage_kernel(
    float* __restrict__ aggio, const float* __restrict__ hin,
    const float* __restrict__ deg,
    const float* __restrict__ Wl, const float* __restrict__ bl,
    const float* __restrict__ Wr, const float* __restrict__ g,
    const float* __restrict__ bet, int N) {
    const int t = threadIdx.x;
    const int nodeBase = blockIdx.x * 4;
    __shared__ float s_mean[4][HID];
    __shared__ float s_h[4][HID];
    __shared__ float s_red[4][2];

#pragma unroll
    for (int n = 0; n < 4; n++) {
        int node = nodeBase + n;
        int cn = node < N ? node : N - 1;
        float d = deg[cn];
        float inv = d > 0.f ? 1.f / d : 0.f;
        s_h[n][t] = hin[cn * HID + t];
        s_mean[n][t] = aggio[cn * HID + t] * inv;
    }
    __syncthreads();

    float acc[4];
    float blf = bl[t];
#pragma unroll
    for (int n = 0; n < 4; n++) acc[n] = blf;
    for (int k = 0; k < HID; k++) {
        float wl = Wl[k * HID + t];
        float wr = Wr[k * HID + t];
#pragma unroll
        for (int n = 0; n < 4; n++)
            acc[n] = fmaf(s_mean[n][k], wl, fmaf(s_h[n][k], wr, acc[n]));
    }

    int lane = t & 63, wid = t >> 6;
#pragma unroll
    for (int n = 0; n < 4; n++) {
        float v = acc[n];
        for (int o = 32; o > 0; o >>= 1) v += __shfl_down(v, o);
        if (lane == 0) s_red[n][wid] = v;
    }
    __syncthreads();
    float mu[4];
#pragma unroll
    for (int n = 0; n < 4; n++) mu[n] = (s_red[n][0] + s_red[n][1]) * (1.f / 128.f);
    __syncthreads();
#pragma unroll
    for (int n = 0; n < 4; n++) {
        float c = acc[n] - mu[n];
        float v = c * c;
        for (int o = 32; o > 0; o >>= 1) v += __shfl_down(v, o);
        if (lane == 0) s_red[n][wid] = v;
    }
    __syncthreads();
    float gf = g[t], bf = bet[t];
#pragma unroll
    for (int n = 0; n < 4; n++) {
        int node = nodeBase + n;
        if (node < N) {
            float var = (s_red[n][0] + s_red[n][1]) * (1.f / 128.f);
            float rstd = rsqrtf(var + 1e-5f);
            float val = (acc[n] - mu[n]) * rstd * gf + bf;
            aggio[node * HID + t] = fmaxf(val, 0.f);
        }
    }
}

// ---- edge MLP prep: transpose+convert weights, convert h to bf16 ----
__global__ void prep_w1(const float* __restrict__ W1, unsigned short* __restrict__ W1T) {
    int i = blockIdx.x * 256 + threadIdx.x;          // over [128][K1]
    if (i >= 128 * K1) return;
    int n = i / K1, k = i - n * K1;
    W1T[i] = (k < 268) ? f2bf(W1[k * HID + n]) : (unsigned short)0;
}
__global__ void prep_w2(const float* __restrict__ W2, unsigned short* __restrict__ W2T) {
    int i = blockIdx.x * 256 + threadIdx.x;          // over [64][128]
    if (i >= 64 * HID) return;
    int n = i >> 7, k = i & 127;
    W2T[i] = f2bf(W2[k * 64 + n]);
}
__global__ void h2bf_kernel(const float* __restrict__ h, unsigned short* __restrict__ o, int total4) {
    int i = blockIdx.x * 256 + threadIdx.x;
    if (i >= total4) return;
    float4 v = ((const float4*)h)[i];
    ushort4 u;
    u.x = f2bf(v.x); u.y = f2bf(v.y); u.z = f2bf(v.z); u.w = f2bf(v.w);
    ((ushort4*)o)[i] = u;
}

// ---- MFMA edge MLP: 64 edges/block, 4 waves, 16x16x32 bf16 ----
__global__ __launch_bounds__(256) void edge_mlp_mfma(
    const unsigned short* __restrict__ hbf,
    const int* __restrict__ src, const int* __restrict__ dst,
    const float* __restrict__ eattr,
    const unsigned short* __restrict__ W1T, const float* __restrict__ b1,
    const unsigned short* __restrict__ W2T, const float* __restrict__ b2,
    const float* __restrict__ W3, const float* __restrict__ b3,
    float* __restrict__ out, int E)
{
    const int t = threadIdx.x;
    const int eBase = blockIdx.x * ET;
    __shared__ __align__(16) unsigned short sA[ET * AS];    // 37888 B; reused as z2 fp32 [64][68]
    __shared__ __align__(16) unsigned short sZ1[ET * Z1S];  // 17408 B
    __shared__ int s_idx[2 * ET];

    if (t < 2 * ET) {
        int eo = t & (ET - 1);
        int e = eBase + eo;
        int ce = e < E ? e : 0;
        s_idx[t] = (t < ET) ? src[ce] : dst[ce];
    }
    __syncthreads();

    // stage A = [h_src(128) | h_dst(128) | eattr(12) | 0-pad] bf16, 4 threads/edge
    {
        const int eo = t >> 2, q = t & 3;
        const uint4* ps = (const uint4*)(hbf + (size_t)s_idx[eo] * HID) + q * 4;
        const uint4* pd = (const uint4*)(hbf + (size_t)s_idx[ET + eo] * HID) + q * 4;
        uint4* das = (uint4*)(&sA[eo * AS + q * 32]);
        uint4* dad = (uint4*)(&sA[eo * AS + 128 + q * 32]);
#pragma unroll
        for (int i = 0; i < 4; i++) das[i] = ps[i];
#pragma unroll
        for (int i = 0; i < 4; i++) dad[i] = pd[i];
        if (q == 3) {
            int e = eBase + eo;
#pragma unroll
            for (int i = 0; i < 12; i++)
                sA[eo * AS + 256 + i] = (e < E) ? f2bf(eattr[(size_t)e * 12 + i]) : (unsigned short)0;
#pragma unroll
            for (int i = 268; i < AS; i++) sA[eo * AS + i] = 0;
        }
    }
    __syncthreads();

    const int wave = t >> 6, lane = t & 63;
    const int ln15 = lane & 15, quad = lane >> 4;
    const int m16 = wave * 16 + ln15;   // A-row this lane supplies

    // layer 1: [64 x 288] @ W1T -> [64 x 128], each wave owns 16 edge-rows
    short8 af[9];
#pragma unroll
    for (int kt = 0; kt < 9; kt++)
        af[kt] = *(const short8*)&sA[m16 * AS + kt * 32 + quad * 8];

#pragma unroll
    for (int nt = 0; nt < 8; nt++) {
        floatx4 acc = {0.f, 0.f, 0.f, 0.f};
#pragma unroll
        for (int kt = 0; kt < 9; kt++) {
            short8 bfr = *(const short8*)&W1T[(nt * 16 + ln15) * K1 + kt * 32 + quad * 8];
            acc = __builtin_amdgcn_mfma_f32_16x16x32_bf16(af[kt], bfr, acc, 0, 0, 0);
        }
        float bias = b1[nt * 16 + ln15];
#pragma unroll
        for (int r = 0; r < 4; r++) {
            int row = wave * 16 + quad * 4 + r;    // D: row=quad*4+reg, col=lane&15
            sZ1[row * Z1S + nt * 16 + ln15] = f2bf(fmaxf(acc[r] + bias, 0.f));
        }
    }
    __syncthreads();   // also orders sA(af) reads before sZ2 overlay writes below

    // layer 2: [64 x 128] @ W2T -> [64 x 64]
    short8 zf[4];
#pragma unroll
    for (int kt = 0; kt < 4; kt++)
        zf[kt] = *(const short8*)&sZ1[m16 * Z1S + kt * 32 + quad * 8];

    float* sZ2 = (float*)sA;   // [64][68] fp32 = 17408 B, overlays dead A-tile
#pragma unroll
    for (int nt = 0; nt < 4; nt++) {
        floatx4 acc = {0.f, 0.f, 0.f, 0.f};
#pragma unroll
        for (int kt = 0; kt < 4; kt++) {
            short8 bfr = *(const short8*)&W2T[(nt * 16 + ln15) * HID + kt * 32 + quad * 8];
            acc = __builtin_amdgcn_mfma_f32_16x16x32_bf16(zf[kt], bfr, acc, 0, 0, 0);
        }
        float bias = b2[nt * 16 + ln15];
#pragma unroll
        for (int r = 0; r < 4; r++) {
            int row = wave * 16 + quad * 4 + r;
            sZ2[row * 68 + nt * 16 + ln15] = fmaxf(acc[r] + bias, 0.f);
        }
    }
    __syncthreads();

    // layer 3 + softplus (fp32), one thread per edge
    if (t < ET) {
        int e = eBase + t;
        if (e < E) {
            float a3 = b3[0];
            const float* z2 = (const float*)sA + t * 68;
#pragma unroll
            for (int k = 0; k < 64; k++) a3 = fmaf(z2[k], W3[k], a3);
            out[e] = fmaxf(a3, 0.f) + log1pf(expf(-fabsf(a3)));
        }
    }
}

extern "C" void kernel_launch(void* const* d_in, const int* in_sizes, int n_in,
                              void* d_out, int out_size, void* d_ws, size_t ws_size,
                              hipStream_t stream) {
    const float* x       = (const float*)d_in[0];
    const int*   ei      = (const int*)d_in[1];
    const float* eattr   = (const float*)d_in[2];
    const float* node_W  = (const float*)d_in[3];
    const float* node_b  = (const float*)d_in[4];
    const float* sage_Wl = (const float*)d_in[5];
    const float* sage_bl = (const float*)d_in[6];
    const float* sage_Wr = (const float*)d_in[7];
    const float* ln_g    = (const float*)d_in[8];
    const float* ln_b    = (const float*)d_in[9];
    const float* W1 = (const float*)d_in[10];
    const float* b1 = (const float*)d_in[11];
    const float* W2 = (const float*)d_in[12];
    const float* b2 = (const float*)d_in[13];
    const float* W3 = (const float*)d_in[14];
    const float* b3 = (const float*)d_in[15];
    float* out = (float*)d_out;

    const int N = in_sizes[0] / 5;
    const int E = in_sizes[1] / 2;
    const int* src  = ei;
    const int* dstp = ei + E;

    size_t hbytes = (size_t)N * HID * sizeof(float);
    char* ws = (char*)d_ws;
    float* bufA = (float*)ws;
    float* bufB = (float*)(ws + hbytes);
    float* deg  = (float*)(ws + 2 * hbytes);

    hipMemsetAsync(deg, 0, (size_t)N * sizeof(float), stream);
    deg_kernel<<<(E + 255) / 256, 256, 0, stream>>>(dstp, deg, E);
    node_proj_kernel<<<(N * HID + 255) / 256, 256, 0, stream>>>(x, node_W, node_b, bufA, N);

    float* hcur = bufA;
    float* other = bufB;
    for (int l = 0; l < 3; l++) {
        hipMemsetAsync(other, 0, hbytes, stream);
        int total = E * HID;
        scatter_kernel<<<(total + 255) / 256, 256, 0, stream>>>(hcur, src, dstp, other, E);
        sage_kernel<<<(N + 3) / 4, 128, 0, stream>>>(
            other, hcur, deg,
            sage_Wl + (size_t)l * HID * HID, sage_bl + (size_t)l * HID,
            sage_Wr + (size_t)l * HID * HID, ln_g + (size_t)l * HID,
            ln_b + (size_t)l * HID, N);
        float* tmp = hcur; hcur = other; other = tmp;
    }

    // edge-MLP scratch lives in the now-stale ping-pong buffer (`other`):
    //   [0, 25.6MB)  h as bf16
    //   [26MB, ...)  W1T bf16 [128][288], then W2T bf16 [64][128]
    unsigned short* hbf = (unsigned short*)other;
    unsigned short* W1T = (unsigned short*)((char*)other + (26u << 20));
    unsigned short* W2T = (unsigned short*)((char*)W1T + 128 * K1 * sizeof(unsigned short));

    int total4 = N * HID / 4;
    h2bf_kernel<<<(total4 + 255) / 256, 256, 0, stream>>>(hcur, hbf, total4);
    prep_w1<<<(128 * K1 + 255) / 256, 256, 0, stream>>>(W1, W1T);
    prep_w2<<<(64 * HID + 255) / 256, 256, 0, stream>>>(W2, W2T);

    edge_mlp_mfma<<<(E + ET - 1) / ET, 256, 0, stream>>>(
        hbf, src, dstp, eattr, W1T, b1, W2T, b2, W3, b3, out, E);
}

// Round 3
// 967.218 us; speedup vs baseline: 3.7830x; 2.2231x over previous
//
#include <hip/hip_runtime.h>
#include <math.h>

#define HID 128
#define ET  64          // edges per block (edge MLP)
#define K1  288         // padded K for layer 1 (268 -> 9*32)
#define Z1S 136         // z1 LDS stride in bf16
#define Z2S 69          // z2 LDS stride in fp32 (odd -> ~2-way banks)

typedef __attribute__((ext_vector_type(8))) short short8;   // 8 bf16 = 4 VGPRs
typedef __attribute__((ext_vector_type(4))) float floatx4;  // MFMA accumulator

static __device__ __forceinline__ unsigned short f2bf(float v) {
    unsigned u = __float_as_uint(v);
    u += 0x7fffu + ((u >> 16) & 1u);   // round-to-nearest-even
    return (unsigned short)(u >> 16);
}

// ---------- CSR build ----------
__global__ void hist_kernel(const int* __restrict__ dst, unsigned* __restrict__ deg, int E) {
    int e = blockIdx.x * 256 + threadIdx.x;
    if (e < E) atomicAdd(&deg[dst[e]], 1u);
}

// per-block exclusive scan of 2048 elems (256 thr x 8), block totals to bsum
__global__ __launch_bounds__(256) void scan_partial(const unsigned* __restrict__ deg,
        unsigned* __restrict__ off, unsigned* __restrict__ bsum, int N) {
    int t = threadIdx.x;
    int base = blockIdx.x * 2048 + t * 8;
    unsigned v[8]; unsigned run = 0;
#pragma unroll
    for (int i = 0; i < 8; i++) {
        int g = base + i;
        unsigned d = (g < N) ? deg[g] : 0u;
        v[i] = run; run += d;
    }
    __shared__ unsigned s[256];
    s[t] = run; __syncthreads();
    for (int o2 = 1; o2 < 256; o2 <<= 1) {
        unsigned x = (t >= o2) ? s[t - o2] : 0u;
        __syncthreads();
        s[t] += x;
        __syncthreads();
    }
    unsigned texcl = (t > 0) ? s[t - 1] : 0u;
    if (t == 255) bsum[blockIdx.x] = s[255];
#pragma unroll
    for (int i = 0; i < 8; i++) {
        int g = base + i;
        if (g < N) off[g] = texcl + v[i];
    }
}

__global__ void scan_bsum(unsigned* bsum, int B) {   // B <= 64, single wave inclusive
    int t = threadIdx.x;
    unsigned v = (t < B) ? bsum[t] : 0u;
    for (int o = 1; o < 64; o <<= 1) {
        unsigned x = __shfl_up(v, o);
        if (t >= o) v += x;
    }
    if (t < B) bsum[t] = v;
}

__global__ void scan_add(unsigned* __restrict__ off, const unsigned* __restrict__ bsum, int N) {
    int g = blockIdx.x * 256 + threadIdx.x;
    if (g >= N) return;
    int blk = g >> 11;
    if (blk > 0) off[g] += bsum[blk - 1];
}

__global__ void csr_fill(const int* __restrict__ src, const int* __restrict__ dst,
                         const unsigned* __restrict__ off, unsigned* __restrict__ cur,
                         int* __restrict__ csr, int E) {
    int e = blockIdx.x * 256 + threadIdx.x;
    if (e >= E) return;
    int d = dst[e];
    unsigned p = off[d] + atomicAdd(&cur[d], 1u);
    csr[p] = src[e];
}

// ---------- node projection ----------
__global__ void node_proj_kernel(const float* __restrict__ x, const float* __restrict__ W,
                                 const float* __restrict__ b, float* __restrict__ h, int N) {
    int i = blockIdx.x * blockDim.x + threadIdx.x;
    if (i >= N * HID) return;
    int n = i >> 7, f = i & 127;
    float acc = b[f];
#pragma unroll
    for (int k = 0; k < 5; k++) acc = fmaf(x[n * 5 + k], W[k * HID + f], acc);
    h[i] = acc;
}

// ---------- mean aggregation over CSR (wave per node, no atomics) ----------
__global__ __launch_bounds__(256) void agg_csr(const float* __restrict__ h,
        const int* __restrict__ csr, const unsigned* __restrict__ off,
        const unsigned* __restrict__ degu, unsigned short* __restrict__ mean_bf, int N) {
    int wid = threadIdx.x >> 6, lane = threadIdx.x & 63;
    int n = blockIdx.x * 4 + wid;
    if (n >= N) return;
    unsigned o = off[n], d = degu[n];
    float2 a0 = {0.f, 0.f}, a1 = {0.f, 0.f};
    unsigned i = 0;
    for (; i + 2 <= d; i += 2) {
        int s0 = csr[o + i], s1 = csr[o + i + 1];
        float2 v0 = *(const float2*)&h[(size_t)s0 * HID + lane * 2];
        float2 v1 = *(const float2*)&h[(size_t)s1 * HID + lane * 2];
        a0.x += v0.x; a0.y += v0.y;
        a1.x += v1.x; a1.y += v1.y;
    }
    if (i < d) {
        int s0 = csr[o + i];
        float2 v0 = *(const float2*)&h[(size_t)s0 * HID + lane * 2];
        a0.x += v0.x; a0.y += v0.y;
    }
    float inv = d ? 1.f / (float)d : 0.f;
    ushort2 u;
    u.x = f2bf((a0.x + a1.x) * inv);
    u.y = f2bf((a0.y + a1.y) * inv);
    *(ushort2*)&mean_bf[(size_t)n * HID + lane * 2] = u;
}

// ---------- SAGE layer: [N x 256] @ [256 x 128] MFMA + bias + LN + ReLU, in-place h ----------
__global__ __launch_bounds__(256) void sage_mfma(
    float* __restrict__ h, const unsigned short* __restrict__ mean_bf,
    const unsigned short* __restrict__ WT,    // [128 out][256 k] bf16 (k<128: Wl, else Wr)
    const float* __restrict__ bl, const float* __restrict__ g,
    const float* __restrict__ bet, int N) {
    const int t = threadIdx.x, wave = t >> 6, lane = t & 63;
    const int ln15 = lane & 15, quad = lane >> 4;
    const int rowBase = blockIdx.x * 64 + wave * 16;
    int m = rowBase + ln15;
    int mc = m < N ? m : N - 1;

    short8 af[8];
#pragma unroll
    for (int kt = 0; kt < 4; kt++)
        af[kt] = *(const short8*)&mean_bf[(size_t)mc * HID + kt * 32 + quad * 8];
#pragma unroll
    for (int kt = 0; kt < 4; kt++) {
        const float* hp = &h[(size_t)mc * HID + kt * 32 + quad * 8];
        float4 p0 = *(const float4*)hp;
        float4 p1 = *(const float4*)(hp + 4);
        short8 a;
        a[0] = (short)f2bf(p0.x); a[1] = (short)f2bf(p0.y);
        a[2] = (short)f2bf(p0.z); a[3] = (short)f2bf(p0.w);
        a[4] = (short)f2bf(p1.x); a[5] = (short)f2bf(p1.y);
        a[6] = (short)f2bf(p1.z); a[7] = (short)f2bf(p1.w);
        af[4 + kt] = a;
    }

    floatx4 acc[8];
#pragma unroll
    for (int nt = 0; nt < 8; nt++) {
        floatx4 a = {0.f, 0.f, 0.f, 0.f};
#pragma unroll
        for (int kt = 0; kt < 8; kt++) {
            short8 b = *(const short8*)&WT[(nt * 16 + ln15) * 256 + kt * 32 + quad * 8];
            a = __builtin_amdgcn_mfma_f32_16x16x32_bf16(af[kt], b, a, 0, 0, 0);
        }
        acc[nt] = a;
    }

    float blv[8], gv[8], bv[8];
#pragma unroll
    for (int nt = 0; nt < 8; nt++) {
        int col = nt * 16 + ln15;
        blv[nt] = bl[col]; gv[nt] = g[col]; bv[nt] = bet[col];
    }
#pragma unroll
    for (int nt = 0; nt < 8; nt++)
#pragma unroll
        for (int r = 0; r < 4; r++) acc[nt][r] += blv[nt];

#pragma unroll
    for (int r = 0; r < 4; r++) {
        float s = 0.f;
#pragma unroll
        for (int nt = 0; nt < 8; nt++) s += acc[nt][r];
        s += __shfl_xor(s, 1); s += __shfl_xor(s, 2);
        s += __shfl_xor(s, 4); s += __shfl_xor(s, 8);
        float mu = s * (1.f / 128.f);
        float q = 0.f;
#pragma unroll
        for (int nt = 0; nt < 8; nt++) { float c = acc[nt][r] - mu; q += c * c; }
        q += __shfl_xor(q, 1); q += __shfl_xor(q, 2);
        q += __shfl_xor(q, 4); q += __shfl_xor(q, 8);
        float rstd = rsqrtf(q * (1.f / 128.f) + 1e-5f);
        int node = rowBase + quad * 4 + r;
        if (node < N) {
            float* hw = &h[(size_t)node * HID];
#pragma unroll
            for (int nt = 0; nt < 8; nt++) {
                float y = (acc[nt][r] - mu) * rstd * gv[nt] + bv[nt];
                hw[nt * 16 + ln15] = fmaxf(y, 0.f);
            }
        }
    }
}

// ---------- weight / activation prep ----------
__global__ void prep_w1(const float* __restrict__ W1, unsigned short* __restrict__ W1T) {
    int i = blockIdx.x * 256 + threadIdx.x;          // over [128][K1]
    if (i >= 128 * K1) return;
    int n = i / K1, k = i - n * K1;
    W1T[i] = (k < 268) ? f2bf(W1[k * HID + n]) : (unsigned short)0;
}
__global__ void prep_w2(const float* __restrict__ W2, unsigned short* __restrict__ W2T) {
    int i = blockIdx.x * 256 + threadIdx.x;          // over [64][128]
    if (i >= 64 * HID) return;
    int n = i >> 7, k = i & 127;
    W2T[i] = f2bf(W2[k * 64 + n]);
}
__global__ void prep_wsage(const float* __restrict__ Wl, const float* __restrict__ Wr,
                           unsigned short* __restrict__ WT) {
    int i = blockIdx.x * 256 + threadIdx.x;          // over 3*[128][256]
    if (i >= 3 * 128 * 256) return;
    int l = i >> 15, rem = i & 32767, n = rem >> 8, k = rem & 255;
    float v = (k < 128) ? Wl[l * 16384 + k * 128 + n] : Wr[l * 16384 + (k - 128) * 128 + n];
    WT[i] = f2bf(v);
}
__global__ void h2bf_kernel(const float* __restrict__ h, unsigned short* __restrict__ o, int total4) {
    int i = blockIdx.x * 256 + threadIdx.x;
    if (i >= total4) return;
    float4 v = ((const float4*)h)[i];
    ushort4 u;
    u.x = f2bf(v.x); u.y = f2bf(v.y); u.z = f2bf(v.z); u.w = f2bf(v.w);
    ((ushort4*)o)[i] = u;
}

// ---------- MFMA edge MLP: 64 edges/block, direct-from-global A fragments ----------
__global__ __launch_bounds__(256) void edge_mlp_mfma(
    const unsigned short* __restrict__ hbf,
    const int* __restrict__ src, const int* __restrict__ dst,
    const float* __restrict__ eattr,
    const unsigned short* __restrict__ W1T, const float* __restrict__ b1,
    const unsigned short* __restrict__ W2T, const float* __restrict__ b2,
    const float* __restrict__ W3, const float* __restrict__ b3,
    float* __restrict__ out, int E)
{
    const int t = threadIdx.x;
    const int eBase = blockIdx.x * ET;
    __shared__ __align__(16) char smem[ET * Z2S * 4];   // 17664 B: z1 bf16 [64][136] / z2 fp32 [64][69]
    unsigned short* sZ1 = (unsigned short*)smem;
    float* sZ2 = (float*)smem;
    __shared__ int s_idx[2 * ET];

    if (t < 2 * ET) {
        int eo = t & (ET - 1);
        int e = eBase + eo;
        int ce = e < E ? e : 0;
        s_idx[t] = (t < ET) ? src[ce] : dst[ce];
    }
    __syncthreads();

    const int wave = t >> 6, lane = t & 63;
    const int ln15 = lane & 15, quad = lane >> 4;
    const int eo = wave * 16 + ln15;
    const int e = eBase + eo;
    const int rs = s_idx[eo], rd = s_idx[ET + eo];

    short8 af[9];
#pragma unroll
    for (int kt = 0; kt < 4; kt++)
        af[kt] = *(const short8*)&hbf[(size_t)rs * HID + kt * 32 + quad * 8];
#pragma unroll
    for (int kt = 0; kt < 4; kt++)
        af[4 + kt] = *(const short8*)&hbf[(size_t)rd * HID + kt * 32 + quad * 8];
    {
        short8 a = {0, 0, 0, 0, 0, 0, 0, 0};
        if (e < E) {
            const float* ep = eattr + (size_t)e * 12;
            if (quad == 0) {
                float4 p0 = *(const float4*)ep, p1 = *(const float4*)(ep + 4);
                a[0] = (short)f2bf(p0.x); a[1] = (short)f2bf(p0.y);
                a[2] = (short)f2bf(p0.z); a[3] = (short)f2bf(p0.w);
                a[4] = (short)f2bf(p1.x); a[5] = (short)f2bf(p1.y);
                a[6] = (short)f2bf(p1.z); a[7] = (short)f2bf(p1.w);
            } else if (quad == 1) {
                float4 p2 = *(const float4*)(ep + 8);
                a[0] = (short)f2bf(p2.x); a[1] = (short)f2bf(p2.y);
                a[2] = (short)f2bf(p2.z); a[3] = (short)f2bf(p2.w);
            }
        }
        af[8] = a;
    }

    // layer 1: [64 x 288] -> [64 x 128]
#pragma unroll
    for (int nt = 0; nt < 8; nt++) {
        floatx4 acc = {0.f, 0.f, 0.f, 0.f};
#pragma unroll
        for (int kt = 0; kt < 9; kt++) {
            short8 b = *(const short8*)&W1T[(nt * 16 + ln15) * K1 + kt * 32 + quad * 8];
            acc = __builtin_amdgcn_mfma_f32_16x16x32_bf16(af[kt], b, acc, 0, 0, 0);
        }
        float bias = b1[nt * 16 + ln15];
#pragma unroll
        for (int r = 0; r < 4; r++) {
            int row = wave * 16 + quad * 4 + r;    // D: row=quad*4+reg, col=lane&15
            sZ1[row * Z1S + nt * 16 + ln15] = f2bf(fmaxf(acc[r] + bias, 0.f));
        }
    }
    __syncthreads();

    short8 zf[4];
#pragma unroll
    for (int kt = 0; kt < 4; kt++)
        zf[kt] = *(const short8*)&sZ1[(wave * 16 + ln15) * Z1S + kt * 32 + quad * 8];
    __syncthreads();    // all zf loaded before z2 overlays z1

    // layer 2: [64 x 128] -> [64 x 64]
#pragma unroll
    for (int nt = 0; nt < 4; nt++) {
        floatx4 acc = {0.f, 0.f, 0.f, 0.f};
#pragma unroll
        for (int kt = 0; kt < 4; kt++) {
            short8 b = *(const short8*)&W2T[(nt * 16 + ln15) * HID + kt * 32 + quad * 8];
            acc = __builtin_amdgcn_mfma_f32_16x16x32_bf16(zf[kt], b, acc, 0, 0, 0);
        }
        float bias = b2[nt * 16 + ln15];
#pragma unroll
        for (int r = 0; r < 4; r++) {
            int row = wave * 16 + quad * 4 + r;
            sZ2[row * Z2S + nt * 16 + ln15] = fmaxf(acc[r] + bias, 0.f);
        }
    }
    __syncthreads();

    // layer 3 + softplus (fp32), one thread per edge
    if (t < ET) {
        int ee = eBase + t;
        if (ee < E) {
            float a3 = b3[0];
            const float* z2 = sZ2 + t * Z2S;
#pragma unroll
            for (int k = 0; k < 64; k++) a3 = fmaf(z2[k], W3[k], a3);
            out[ee] = fmaxf(a3, 0.f) + log1pf(expf(-fabsf(a3)));
        }
    }
}

extern "C" void kernel_launch(void* const* d_in, const int* in_sizes, int n_in,
                              void* d_out, int out_size, void* d_ws, size_t ws_size,
                              hipStream_t stream) {
    const float* x       = (const float*)d_in[0];
    const int*   ei      = (const int*)d_in[1];
    const float* eattr   = (const float*)d_in[2];
    const float* node_W  = (const float*)d_in[3];
    const float* node_b  = (const float*)d_in[4];
    const float* sage_Wl = (const float*)d_in[5];
    const float* sage_bl = (const float*)d_in[6];
    const float* sage_Wr = (const float*)d_in[7];
    const float* ln_g    = (const float*)d_in[8];
    const float* ln_b    = (const float*)d_in[9];
    const float* W1 = (const float*)d_in[10];
    const float* b1 = (const float*)d_in[11];
    const float* W2 = (const float*)d_in[12];
    const float* b2 = (const float*)d_in[13];
    const float* W3 = (const float*)d_in[14];
    const float* b3 = (const float*)d_in[15];
    float* out = (float*)d_out;

    const int N = in_sizes[0] / 5;
    const int E = in_sizes[1] / 2;
    const int* src  = ei;
    const int* dstp = ei + E;

    // workspace layout (~82 MB total; round-1 proved >=103 MB available)
    char* ws = (char*)d_ws;
    size_t cur_off = 0;
    auto alloc = [&](size_t bytes) { size_t p = cur_off; cur_off = (cur_off + bytes + 255) & ~(size_t)255; return p; };
    float*          h      = (float*)(ws + alloc((size_t)N * HID * 4));
    unsigned short* meanbf = (unsigned short*)(ws + alloc((size_t)N * HID * 2));  // reused as hbf
    int*            csr    = (int*)(ws + alloc((size_t)E * 4));
    unsigned*       degu   = (unsigned*)(ws + alloc((size_t)N * 4));
    unsigned*       curp   = (unsigned*)(ws + alloc((size_t)N * 4));
    unsigned*       offs   = (unsigned*)(ws + alloc((size_t)N * 4));
    unsigned*       bsum   = (unsigned*)(ws + alloc(64 * 4));
    unsigned short* W1T    = (unsigned short*)(ws + alloc(128 * K1 * 2));
    unsigned short* W2T    = (unsigned short*)(ws + alloc(64 * HID * 2));
    unsigned short* WST    = (unsigned short*)(ws + alloc(3 * 128 * 256 * 2));

    hipMemsetAsync(degu, 0, (size_t)N * sizeof(unsigned), stream);
    hipMemsetAsync(curp, 0, (size_t)N * sizeof(unsigned), stream);
    hist_kernel<<<(E + 255) / 256, 256, 0, stream>>>(dstp, degu, E);
    int NB = (N + 2047) / 2048;   // 49 for N=100000, fits the 64-lane bsum scan
    scan_partial<<<NB, 256, 0, stream>>>(degu, offs, bsum, N);
    scan_bsum<<<1, 64, 0, stream>>>(bsum, NB);
    scan_add<<<(N + 255) / 256, 256, 0, stream>>>(offs, bsum, N);
    csr_fill<<<(E + 255) / 256, 256, 0, stream>>>(src, dstp, offs, curp, csr, E);

    prep_w1<<<(128 * K1 + 255) / 256, 256, 0, stream>>>(W1, W1T);
    prep_w2<<<(64 * HID + 255) / 256, 256, 0, stream>>>(W2, W2T);
    prep_wsage<<<(3 * 128 * 256 + 255) / 256, 256, 0, stream>>>(sage_Wl, sage_Wr, WST);

    node_proj_kernel<<<(N * HID + 255) / 256, 256, 0, stream>>>(x, node_W, node_b, h, N);

    for (int l = 0; l < 3; l++) {
        agg_csr<<<(N + 3) / 4, 256, 0, stream>>>(h, csr, offs, degu, meanbf, N);
        sage_mfma<<<(N + 63) / 64, 256, 0, stream>>>(
            h, meanbf, WST + (size_t)l * 128 * 256,
            sage_bl + (size_t)l * HID, ln_g + (size_t)l * HID, ln_b + (size_t)l * HID, N);
    }

    int total4 = N * HID / 4;
    h2bf_kernel<<<(total4 + 255) / 256, 256, 0, stream>>>(h, meanbf, total4);

    edge_mlp_mfma<<<(E + ET - 1) / ET, 256, 0, stream>>>(
        meanbf, src, dstp, eattr, W1T, b1, W2T, b2, W3, b3, out, E);
}

// Round 4
// 754.499 us; speedup vs baseline: 4.8495x; 1.2819x over previous
//
#include <hip/hip_runtime.h>
#include <math.h>

#define HID 128
#define ET  128         // edges per block (edge MLP)
#define K1  288         // padded K for layer 1 (268 -> 9*32)
#define Z1S 136         // z1 LDS stride in bf16 (272 B, 16B-aligned, 2-way banks on reads)
#define Z2S 69          // z2 LDS stride in fp32

typedef __attribute__((ext_vector_type(8))) short short8;   // 8 bf16 = 4 VGPRs
typedef __attribute__((ext_vector_type(4))) float floatx4;  // MFMA accumulator

static __device__ __forceinline__ unsigned short f2bf(float v) {
    unsigned u = __float_as_uint(v);
    u += 0x7fffu + ((u >> 16) & 1u);   // round-to-nearest-even
    return (unsigned short)(u >> 16);
}
static __device__ __forceinline__ float bf2f_lo(unsigned u) { return __uint_as_float(u << 16); }
static __device__ __forceinline__ float bf2f_hi(unsigned u) { return __uint_as_float(u & 0xffff0000u); }

// ---------- CSR build ----------
__global__ void hist_kernel(const int* __restrict__ dst, unsigned* __restrict__ deg, int E) {
    int e = blockIdx.x * 256 + threadIdx.x;
    if (e < E) atomicAdd(&deg[dst[e]], 1u);
}

__global__ __launch_bounds__(256) void scan_partial(const unsigned* __restrict__ deg,
        unsigned* __restrict__ off, unsigned* __restrict__ bsum, int N) {
    int t = threadIdx.x;
    int base = blockIdx.x * 2048 + t * 8;
    unsigned v[8]; unsigned run = 0;
#pragma unroll
    for (int i = 0; i < 8; i++) {
        int g = base + i;
        unsigned d = (g < N) ? deg[g] : 0u;
        v[i] = run; run += d;
    }
    __shared__ unsigned s[256];
    s[t] = run; __syncthreads();
    for (int o2 = 1; o2 < 256; o2 <<= 1) {
        unsigned x = (t >= o2) ? s[t - o2] : 0u;
        __syncthreads();
        s[t] += x;
        __syncthreads();
    }
    unsigned texcl = (t > 0) ? s[t - 1] : 0u;
    if (t == 255) bsum[blockIdx.x] = s[255];
#pragma unroll
    for (int i = 0; i < 8; i++) {
        int g = base + i;
        if (g < N) off[g] = texcl + v[i];
    }
}

__global__ void scan_bsum(unsigned* bsum, int B) {   // B <= 64, single wave inclusive
    int t = threadIdx.x;
    unsigned v = (t < B) ? bsum[t] : 0u;
    for (int o = 1; o < 64; o <<= 1) {
        unsigned x = __shfl_up(v, o);
        if (t >= o) v += x;
    }
    if (t < B) bsum[t] = v;
}

__global__ void scan_add(unsigned* __restrict__ off, const unsigned* __restrict__ bsum, int N) {
    int g = blockIdx.x * 256 + threadIdx.x;
    if (g >= N) return;
    int blk = g >> 11;
    if (blk > 0) off[g] += bsum[blk - 1];
}

__global__ void csr_fill(const int* __restrict__ src, const int* __restrict__ dst,
                         const unsigned* __restrict__ off, unsigned* __restrict__ cur,
                         int* __restrict__ csr, int E) {
    int e = blockIdx.x * 256 + threadIdx.x;
    if (e >= E) return;
    int d = dst[e];
    unsigned p = off[d] + atomicAdd(&cur[d], 1u);
    csr[p] = src[e];
}

// ---------- node projection (writes bf16 h) ----------
__global__ void node_proj_kernel(const float* __restrict__ x, const float* __restrict__ W,
                                 const float* __restrict__ b, unsigned short* __restrict__ hbf, int N) {
    int i = blockIdx.x * 256 + threadIdx.x;   // over N*64, 2 cols/thread
    if (i >= N * 64) return;
    int n = i >> 6, f2 = (i & 63) * 2;
    float a0 = b[f2], a1 = b[f2 + 1];
#pragma unroll
    for (int k = 0; k < 5; k++) {
        float xv = x[n * 5 + k];
        a0 = fmaf(xv, W[k * HID + f2], a0);
        a1 = fmaf(xv, W[k * HID + f2 + 1], a1);
    }
    unsigned pack = ((unsigned)f2bf(a1) << 16) | f2bf(a0);
    *(unsigned*)&hbf[(size_t)n * HID + f2] = pack;
}

// ---------- mean aggregation over CSR: wave per node, 8 rows in flight ----------
__global__ __launch_bounds__(256) void agg_csr(const unsigned short* __restrict__ hbf,
        const int* __restrict__ csr, const unsigned* __restrict__ off,
        const unsigned* __restrict__ degu, unsigned short* __restrict__ mean_bf, int N) {
    int wid = threadIdx.x >> 6, lane = threadIdx.x & 63;
    int n = blockIdx.x * 4 + wid;
    if (n >= N) return;
    unsigned o = off[n], d = degu[n];
    float a0 = 0.f, a1 = 0.f;
    unsigned i = 0;
    for (; i + 8 <= d; i += 8) {
        unsigned v[8];
#pragma unroll
        for (int j = 0; j < 8; j++) {
            int s = csr[o + i + j];
            v[j] = *(const unsigned*)&hbf[(size_t)s * HID + lane * 2];
        }
#pragma unroll
        for (int j = 0; j < 8; j++) { a0 += bf2f_lo(v[j]); a1 += bf2f_hi(v[j]); }
    }
    for (; i < d; i++) {
        int s = csr[o + i];
        unsigned v = *(const unsigned*)&hbf[(size_t)s * HID + lane * 2];
        a0 += bf2f_lo(v); a1 += bf2f_hi(v);
    }
    float inv = d ? 1.f / (float)d : 0.f;
    unsigned pack = ((unsigned)f2bf(a1 * inv) << 16) | f2bf(a0 * inv);
    *(unsigned*)&mean_bf[(size_t)n * HID + lane * 2] = pack;
}

// ---------- SAGE layer: [N x 256] @ [256 x 128] + bias + LN + ReLU, bf16 h in-place ----------
// 128 nodes/block, wave owns 2 M-tiles -> each B-frag load feeds 2 MFMAs.
__global__ __launch_bounds__(256) void sage_mfma(
    unsigned short* __restrict__ hbf, const unsigned short* __restrict__ mean_bf,
    const unsigned short* __restrict__ WT,    // [128 out][256 k] bf16 (k<128: Wl, else Wr)
    const float* __restrict__ bl, const float* __restrict__ g,
    const float* __restrict__ bet, int N) {
    const int t = threadIdx.x, wave = t >> 6, lane = t & 63;
    const int ln15 = lane & 15, quad = lane >> 4;
    const int blkBase = blockIdx.x * 128;

    short8 af[2][8];
#pragma unroll
    for (int tt = 0; tt < 2; tt++) {
        int m = blkBase + tt * 64 + wave * 16 + ln15;
        int mc = m < N ? m : N - 1;
#pragma unroll
        for (int kt = 0; kt < 4; kt++)
            af[tt][kt] = *(const short8*)&mean_bf[(size_t)mc * HID + kt * 32 + quad * 8];
#pragma unroll
        for (int kt = 0; kt < 4; kt++)
            af[tt][4 + kt] = *(const short8*)&hbf[(size_t)mc * HID + kt * 32 + quad * 8];
    }

    floatx4 acc[2][8];
#pragma unroll
    for (int nt = 0; nt < 8; nt++) {
        floatx4 a0 = {0.f, 0.f, 0.f, 0.f}, a1 = {0.f, 0.f, 0.f, 0.f};
#pragma unroll
        for (int kt = 0; kt < 8; kt++) {
            short8 b = *(const short8*)&WT[(nt * 16 + ln15) * 256 + kt * 32 + quad * 8];
            a0 = __builtin_amdgcn_mfma_f32_16x16x32_bf16(af[0][kt], b, a0, 0, 0, 0);
            a1 = __builtin_amdgcn_mfma_f32_16x16x32_bf16(af[1][kt], b, a1, 0, 0, 0);
        }
        acc[0][nt] = a0; acc[1][nt] = a1;
    }

    float blv[8], gv[8], bv[8];
#pragma unroll
    for (int nt = 0; nt < 8; nt++) {
        int col = nt * 16 + ln15;
        blv[nt] = bl[col]; gv[nt] = g[col]; bv[nt] = bet[col];
    }

#pragma unroll
    for (int tt = 0; tt < 2; tt++) {
#pragma unroll
        for (int r = 0; r < 4; r++) {
            float s = 0.f;
#pragma unroll
            for (int nt = 0; nt < 8; nt++) s += acc[tt][nt][r] + blv[nt];
            s += __shfl_xor(s, 1); s += __shfl_xor(s, 2);
            s += __shfl_xor(s, 4); s += __shfl_xor(s, 8);
            float mu = s * (1.f / 128.f);
            float q = 0.f;
#pragma unroll
            for (int nt = 0; nt < 8; nt++) { float c = acc[tt][nt][r] + blv[nt] - mu; q += c * c; }
            q += __shfl_xor(q, 1); q += __shfl_xor(q, 2);
            q += __shfl_xor(q, 4); q += __shfl_xor(q, 8);
            float rstd = rsqrtf(q * (1.f / 128.f) + 1e-5f);
            int node = blkBase + tt * 64 + wave * 16 + quad * 4 + r;
#pragma unroll
            for (int nt = 0; nt < 8; nt++) {
                float y = fmaxf((acc[tt][nt][r] + blv[nt] - mu) * rstd * gv[nt] + bv[nt], 0.f);
                float yp = __shfl_xor(y, 1);
                if (node < N && !(ln15 & 1)) {
                    unsigned pack = ((unsigned)f2bf(yp) << 16) | f2bf(y);
                    *(unsigned*)&hbf[(size_t)node * HID + nt * 16 + ln15] = pack;
                }
            }
        }
    }
}

// ---------- weight prep ----------
__global__ void prep_w1(const float* __restrict__ W1, unsigned short* __restrict__ W1T) {
    int i = blockIdx.x * 256 + threadIdx.x;          // over [128][K1]
    if (i >= 128 * K1) return;
    int n = i / K1, k = i - n * K1;
    W1T[i] = (k < 268) ? f2bf(W1[k * HID + n]) : (unsigned short)0;
}
__global__ void prep_w2(const float* __restrict__ W2, unsigned short* __restrict__ W2T) {
    int i = blockIdx.x * 256 + threadIdx.x;          // over [64][128]
    if (i >= 64 * HID) return;
    int n = i >> 7, k = i & 127;
    W2T[i] = f2bf(W2[k * 64 + n]);
}
__global__ void prep_wsage(const float* __restrict__ Wl, const float* __restrict__ Wr,
                           unsigned short* __restrict__ WT) {
    int i = blockIdx.x * 256 + threadIdx.x;          // over 3*[128][256]
    if (i >= 3 * 128 * 256) return;
    int l = i >> 15, rem = i & 32767, n = rem >> 8, k = rem & 255;
    float v = (k < 128) ? Wl[l * 16384 + k * 128 + n] : Wr[l * 16384 + (k - 128) * 128 + n];
    WT[i] = f2bf(v);
}

// ---------- MFMA edge MLP: 128 edges/block, 2 M-tiles/wave ----------
__global__ __launch_bounds__(256) void edge_mlp_mfma(
    const unsigned short* __restrict__ hbf,
    const int* __restrict__ src, const int* __restrict__ dst,
    const float* __restrict__ eattr,
    const unsigned short* __restrict__ W1T, const float* __restrict__ b1,
    const unsigned short* __restrict__ W2T, const float* __restrict__ b2,
    const float* __restrict__ W3, const float* __restrict__ b3,
    float* __restrict__ out, int E)
{
    const int t = threadIdx.x;
    const int eBase = blockIdx.x * ET;
    __shared__ __align__(16) char smem[ET * Z2S * 4];   // 35328 B: z1 bf16 [128][136] / z2 fp32 [128][69]
    unsigned short* sZ1 = (unsigned short*)smem;
    float* sZ2 = (float*)smem;
    __shared__ int s_idx[2 * ET];

    {
        int eo = t & (ET - 1);
        int e = eBase + eo;
        int ce = e < E ? e : 0;
        s_idx[t] = (t < ET) ? src[ce] : dst[ce];
    }
    __syncthreads();

    const int wave = t >> 6, lane = t & 63;
    const int ln15 = lane & 15, quad = lane >> 4;

    short8 af[2][9];
#pragma unroll
    for (int tt = 0; tt < 2; tt++) {
        int eo = tt * 64 + wave * 16 + ln15;
        int rs = s_idx[eo], rd = s_idx[ET + eo];
#pragma unroll
        for (int kt = 0; kt < 4; kt++)
            af[tt][kt] = *(const short8*)&hbf[(size_t)rs * HID + kt * 32 + quad * 8];
#pragma unroll
        for (int kt = 0; kt < 4; kt++)
            af[tt][4 + kt] = *(const short8*)&hbf[(size_t)rd * HID + kt * 32 + quad * 8];
        short8 a = {0, 0, 0, 0, 0, 0, 0, 0};
        int e = eBase + eo;
        if (e < E) {
            const float* ep = eattr + (size_t)e * 12;
            if (quad == 0) {
                float4 p0 = *(const float4*)ep, p1 = *(const float4*)(ep + 4);
                a[0] = (short)f2bf(p0.x); a[1] = (short)f2bf(p0.y);
                a[2] = (short)f2bf(p0.z); a[3] = (short)f2bf(p0.w);
                a[4] = (short)f2bf(p1.x); a[5] = (short)f2bf(p1.y);
                a[6] = (short)f2bf(p1.z); a[7] = (short)f2bf(p1.w);
            } else if (quad == 1) {
                float4 p2 = *(const float4*)(ep + 8);
                a[0] = (short)f2bf(p2.x); a[1] = (short)f2bf(p2.y);
                a[2] = (short)f2bf(p2.z); a[3] = (short)f2bf(p2.w);
            }
        }
        af[tt][8] = a;
    }

    // layer 1: [128 x 288] -> [128 x 128]; B-frag loaded once per (nt,kt), used by both tiles
#pragma unroll
    for (int nt = 0; nt < 8; nt++) {
        floatx4 a0 = {0.f, 0.f, 0.f, 0.f}, a1 = {0.f, 0.f, 0.f, 0.f};
#pragma unroll
        for (int kt = 0; kt < 9; kt++) {
            short8 b = *(const short8*)&W1T[(nt * 16 + ln15) * K1 + kt * 32 + quad * 8];
            a0 = __builtin_amdgcn_mfma_f32_16x16x32_bf16(af[0][kt], b, a0, 0, 0, 0);
            a1 = __builtin_amdgcn_mfma_f32_16x16x32_bf16(af[1][kt], b, a1, 0, 0, 0);
        }
        float bias = b1[nt * 16 + ln15];
#pragma unroll
        for (int r = 0; r < 4; r++) {
            float y0 = fmaxf(a0[r] + bias, 0.f);
            float y1 = fmaxf(a1[r] + bias, 0.f);
            float y0p = __shfl_xor(y0, 1);
            float y1p = __shfl_xor(y1, 1);
            if (!(ln15 & 1)) {
                int row0 = wave * 16 + quad * 4 + r;
                unsigned pk0 = ((unsigned)f2bf(y0p) << 16) | f2bf(y0);
                unsigned pk1 = ((unsigned)f2bf(y1p) << 16) | f2bf(y1);
                *(unsigned*)&sZ1[row0 * Z1S + nt * 16 + ln15] = pk0;
                *(unsigned*)&sZ1[(64 + row0) * Z1S + nt * 16 + ln15] = pk1;
            }
        }
    }
    __syncthreads();

    short8 zf[2][4];
#pragma unroll
    for (int tt = 0; tt < 2; tt++)
#pragma unroll
        for (int kt = 0; kt < 4; kt++)
            zf[tt][kt] = *(const short8*)&sZ1[(tt * 64 + wave * 16 + ln15) * Z1S + kt * 32 + quad * 8];
    __syncthreads();    // zf loaded before z2 overlays z1

    // layer 2: [128 x 128] -> [128 x 64]
#pragma unroll
    for (int nt = 0; nt < 4; nt++) {
        floatx4 a0 = {0.f, 0.f, 0.f, 0.f}, a1 = {0.f, 0.f, 0.f, 0.f};
#pragma unroll
        for (int kt = 0; kt < 4; kt++) {
            short8 b = *(const short8*)&W2T[(nt * 16 + ln15) * HID + kt * 32 + quad * 8];
            a0 = __builtin_amdgcn_mfma_f32_16x16x32_bf16(zf[0][kt], b, a0, 0, 0, 0);
            a1 = __builtin_amdgcn_mfma_f32_16x16x32_bf16(zf[1][kt], b, a1, 0, 0, 0);
        }
        float bias = b2[nt * 16 + ln15];
#pragma unroll
        for (int r = 0; r < 4; r++) {
            int row0 = wave * 16 + quad * 4 + r;
            sZ2[row0 * Z2S + nt * 16 + ln15] = fmaxf(a0[r] + bias, 0.f);
            sZ2[(64 + row0) * Z2S + nt * 16 + ln15] = fmaxf(a1[r] + bias, 0.f);
        }
    }
    __syncthreads();

    // layer 3 + softplus (fp32), one thread per edge
    if (t < ET) {
        int ee = eBase + t;
        if (ee < E) {
            float a3 = b3[0];
            const float* z2 = sZ2 + t * Z2S;
#pragma unroll
            for (int k = 0; k < 64; k++) a3 = fmaf(z2[k], W3[k], a3);
            out[ee] = fmaxf(a3, 0.f) + log1pf(expf(-fabsf(a3)));
        }
    }
}

extern "C" void kernel_launch(void* const* d_in, const int* in_sizes, int n_in,
                              void* d_out, int out_size, void* d_ws, size_t ws_size,
                              hipStream_t stream) {
    const float* x       = (const float*)d_in[0];
    const int*   ei      = (const int*)d_in[1];
    const float* eattr   = (const float*)d_in[2];
    const float* node_W  = (const float*)d_in[3];
    const float* node_b  = (const float*)d_in[4];
    const float* sage_Wl = (const float*)d_in[5];
    const float* sage_bl = (const float*)d_in[6];
    const float* sage_Wr = (const float*)d_in[7];
    const float* ln_g    = (const float*)d_in[8];
    const float* ln_b    = (const float*)d_in[9];
    const float* W1 = (const float*)d_in[10];
    const float* b1 = (const float*)d_in[11];
    const float* W2 = (const float*)d_in[12];
    const float* b2 = (const float*)d_in[13];
    const float* W3 = (const float*)d_in[14];
    const float* b3 = (const float*)d_in[15];
    float* out = (float*)d_out;

    const int N = in_sizes[0] / 5;
    const int E = in_sizes[1] / 2;
    const int* src  = ei;
    const int* dstp = ei + E;

    char* ws = (char*)d_ws;
    size_t cur_off = 0;
    auto alloc = [&](size_t bytes) { size_t p = cur_off; cur_off = (cur_off + bytes + 255) & ~(size_t)255; return p; };
    unsigned short* hbf    = (unsigned short*)(ws + alloc((size_t)N * HID * 2));
    unsigned short* meanbf = (unsigned short*)(ws + alloc((size_t)N * HID * 2));
    int*            csr    = (int*)(ws + alloc((size_t)E * 4));
    unsigned*       degu   = (unsigned*)(ws + alloc((size_t)N * 4));
    unsigned*       curp   = (unsigned*)(ws + alloc((size_t)N * 4));
    unsigned*       offs   = (unsigned*)(ws + alloc((size_t)N * 4));
    unsigned*       bsum   = (unsigned*)(ws + alloc(64 * 4));
    unsigned short* W1T    = (unsigned short*)(ws + alloc(128 * K1 * 2));
    unsigned short* W2T    = (unsigned short*)(ws + alloc(64 * HID * 2));
    unsigned short* WST    = (unsigned short*)(ws + alloc(3 * 128 * 256 * 2));

    hipMemsetAsync(degu, 0, (size_t)N * sizeof(unsigned), stream);
    hipMemsetAsync(curp, 0, (size_t)N * sizeof(unsigned), stream);
    hist_kernel<<<(E + 255) / 256, 256, 0, stream>>>(dstp, degu, E);
    int NB = (N + 2047) / 2048;   // 49 for N=100000, fits the 64-lane bsum scan
    scan_partial<<<NB, 256, 0, stream>>>(degu, offs, bsum, N);
    scan_bsum<<<1, 64, 0, stream>>>(bsum, NB);
    scan_add<<<(N + 255) / 256, 256, 0, stream>>>(offs, bsum, N);
    csr_fill<<<(E + 255) / 256, 256, 0, stream>>>(src, dstp, offs, curp, csr, E);

    prep_w1<<<(128 * K1 + 255) / 256, 256, 0, stream>>>(W1, W1T);
    prep_w2<<<(64 * HID + 255) / 256, 256, 0, stream>>>(W2, W2T);
    prep_wsage<<<(3 * 128 * 256 + 255) / 256, 256, 0, stream>>>(sage_Wl, sage_Wr, WST);

    node_proj_kernel<<<(N * 64 + 255) / 256, 256, 0, stream>>>(x, node_W, node_b, hbf, N);

    for (int l = 0; l < 3; l++) {
        agg_csr<<<(N + 3) / 4, 256, 0, stream>>>(hbf, csr, offs, degu, meanbf, N);
        sage_mfma<<<(N + 127) / 128, 256, 0, stream>>>(
            hbf, meanbf, WST + (size_t)l * 128 * 256,
            sage_bl + (size_t)l * HID, ln_g + (size_t)l * HID, ln_b + (size_t)l * HID, N);
    }

    edge_mlp_mfma<<<(E + ET - 1) / ET, 256, 0, stream>>>(
        hbf, src, dstp, eattr, W1T, b1, W2T, b2, W3, b3, out, E);
}

// Round 5
// 698.696 us; speedup vs baseline: 5.2369x; 1.0799x over previous
//
#include <hip/hip_runtime.h>
#include <math.h>

#define HID 128
#define ET  256         // edges per block (edge MLP), 4 M-tiles per wave
#define K1  288         // padded K for layer 1 (268 -> 9*32)
#define Z1S 136         // z1 LDS stride in bf16
#define Z2S 69          // z2 LDS stride in fp32

typedef __attribute__((ext_vector_type(8))) short short8;   // 8 bf16 = 4 VGPRs
typedef __attribute__((ext_vector_type(4))) float floatx4;  // MFMA accumulator

static __device__ __forceinline__ unsigned short f2bf(float v) {
    unsigned u = __float_as_uint(v);
    u += 0x7fffu + ((u >> 16) & 1u);   // round-to-nearest-even
    return (unsigned short)(u >> 16);
}
static __device__ __forceinline__ float bf2f_lo(unsigned u) { return __uint_as_float(u << 16); }
static __device__ __forceinline__ float bf2f_hi(unsigned u) { return __uint_as_float(u & 0xffff0000u); }

// ---------- CSR build ----------
__global__ void hist_kernel(const int* __restrict__ dst, unsigned* __restrict__ deg, int E) {
    int e = blockIdx.x * 256 + threadIdx.x;
    if (e < E) atomicAdd(&deg[dst[e]], 1u);
}

__global__ __launch_bounds__(256) void scan_partial(const unsigned* __restrict__ deg,
        unsigned* __restrict__ off, unsigned* __restrict__ bsum, int N) {
    int t = threadIdx.x;
    int base = blockIdx.x * 2048 + t * 8;
    unsigned v[8]; unsigned run = 0;
#pragma unroll
    for (int i = 0; i < 8; i++) {
        int g = base + i;
        unsigned d = (g < N) ? deg[g] : 0u;
        v[i] = run; run += d;
    }
    __shared__ unsigned s[256];
    s[t] = run; __syncthreads();
    for (int o2 = 1; o2 < 256; o2 <<= 1) {
        unsigned x = (t >= o2) ? s[t - o2] : 0u;
        __syncthreads();
        s[t] += x;
        __syncthreads();
    }
    unsigned texcl = (t > 0) ? s[t - 1] : 0u;
    if (t == 255) bsum[blockIdx.x] = s[255];
#pragma unroll
    for (int i = 0; i < 8; i++) {
        int g = base + i;
        if (g < N) off[g] = texcl + v[i];
    }
}

__global__ void scan_bsum(unsigned* bsum, int B) {   // B <= 64, single wave inclusive
    int t = threadIdx.x;
    unsigned v = (t < B) ? bsum[t] : 0u;
    for (int o = 1; o < 64; o <<= 1) {
        unsigned x = __shfl_up(v, o);
        if (t >= o) v += x;
    }
    if (t < B) bsum[t] = v;
}

__global__ void scan_add(unsigned* __restrict__ off, const unsigned* __restrict__ bsum, int N) {
    int g = blockIdx.x * 256 + threadIdx.x;
    if (g >= N) return;
    int blk = g >> 11;
    if (blk > 0) off[g] += bsum[blk - 1];
}

__global__ void csr_fill(const int* __restrict__ src, const int* __restrict__ dst,
                         const unsigned* __restrict__ off, unsigned* __restrict__ cur,
                         int* __restrict__ csr, int E) {
    int e = blockIdx.x * 256 + threadIdx.x;
    if (e >= E) return;
    int d = dst[e];
    unsigned p = off[d] + atomicAdd(&cur[d], 1u);
    csr[p] = src[e];
}

// ---------- node projection (writes bf16 h) ----------
__global__ void node_proj_kernel(const float* __restrict__ x, const float* __restrict__ W,
                                 const float* __restrict__ b, unsigned short* __restrict__ hbf, int N) {
    int i = blockIdx.x * 256 + threadIdx.x;   // over N*64, 2 cols/thread
    if (i >= N * 64) return;
    int n = i >> 6, f2 = (i & 63) * 2;
    float a0 = b[f2], a1 = b[f2 + 1];
#pragma unroll
    for (int k = 0; k < 5; k++) {
        float xv = x[n * 5 + k];
        a0 = fmaf(xv, W[k * HID + f2], a0);
        a1 = fmaf(xv, W[k * HID + f2 + 1], a1);
    }
    unsigned pack = ((unsigned)f2bf(a1) << 16) | f2bf(a0);
    *(unsigned*)&hbf[(size_t)n * HID + f2] = pack;
}

// ---------- mean aggregation: 4 nodes per wave, 16 lanes x ushort8 per row ----------
__global__ __launch_bounds__(256) void agg_csr(const unsigned short* __restrict__ hbf,
        const int* __restrict__ csr, const unsigned* __restrict__ off,
        const unsigned* __restrict__ degu, unsigned short* __restrict__ mean_bf, int N) {
    const int wv = threadIdx.x >> 6, lane = threadIdx.x & 63;
    const int g = lane >> 4, c = lane & 15;
    const int n = (blockIdx.x * 4 + wv) * 4 + g;
    const int nc = n < N ? n : N - 1;
    const unsigned o = off[nc];
    const unsigned d = (n < N) ? degu[nc] : 0u;
    unsigned dmax = d;
    dmax = max(dmax, (unsigned)__shfl_xor((int)dmax, 16));
    dmax = max(dmax, (unsigned)__shfl_xor((int)dmax, 32));

    float acc[8] = {0.f, 0.f, 0.f, 0.f, 0.f, 0.f, 0.f, 0.f};
    for (unsigned i = 0; i < dmax; i += 4) {
        unsigned p0 = (i     < d) ? o + i     : 0u;
        unsigned p1 = (i + 1 < d) ? o + i + 1 : 0u;
        unsigned p2 = (i + 2 < d) ? o + i + 2 : 0u;
        unsigned p3 = (i + 3 < d) ? o + i + 3 : 0u;
        int s0 = csr[p0], s1 = csr[p1], s2 = csr[p2], s3 = csr[p3];
        uint4 v0 = *(const uint4*)&hbf[(size_t)s0 * HID + c * 8];
        uint4 v1 = *(const uint4*)&hbf[(size_t)s1 * HID + c * 8];
        uint4 v2 = *(const uint4*)&hbf[(size_t)s2 * HID + c * 8];
        uint4 v3 = *(const uint4*)&hbf[(size_t)s3 * HID + c * 8];
        if (i < d) {
            acc[0] += bf2f_lo(v0.x); acc[1] += bf2f_hi(v0.x);
            acc[2] += bf2f_lo(v0.y); acc[3] += bf2f_hi(v0.y);
            acc[4] += bf2f_lo(v0.z); acc[5] += bf2f_hi(v0.z);
            acc[6] += bf2f_lo(v0.w); acc[7] += bf2f_hi(v0.w);
        }
        if (i + 1 < d) {
            acc[0] += bf2f_lo(v1.x); acc[1] += bf2f_hi(v1.x);
            acc[2] += bf2f_lo(v1.y); acc[3] += bf2f_hi(v1.y);
            acc[4] += bf2f_lo(v1.z); acc[5] += bf2f_hi(v1.z);
            acc[6] += bf2f_lo(v1.w); acc[7] += bf2f_hi(v1.w);
        }
        if (i + 2 < d) {
            acc[0] += bf2f_lo(v2.x); acc[1] += bf2f_hi(v2.x);
            acc[2] += bf2f_lo(v2.y); acc[3] += bf2f_hi(v2.y);
            acc[4] += bf2f_lo(v2.z); acc[5] += bf2f_hi(v2.z);
            acc[6] += bf2f_lo(v2.w); acc[7] += bf2f_hi(v2.w);
        }
        if (i + 3 < d) {
            acc[0] += bf2f_lo(v3.x); acc[1] += bf2f_hi(v3.x);
            acc[2] += bf2f_lo(v3.y); acc[3] += bf2f_hi(v3.y);
            acc[4] += bf2f_lo(v3.z); acc[5] += bf2f_hi(v3.z);
            acc[6] += bf2f_lo(v3.w); acc[7] += bf2f_hi(v3.w);
        }
    }
    if (n < N) {
        float inv = d ? 1.f / (float)d : 0.f;
        uint4 p;
        p.x = ((unsigned)f2bf(acc[1] * inv) << 16) | f2bf(acc[0] * inv);
        p.y = ((unsigned)f2bf(acc[3] * inv) << 16) | f2bf(acc[2] * inv);
        p.z = ((unsigned)f2bf(acc[5] * inv) << 16) | f2bf(acc[4] * inv);
        p.w = ((unsigned)f2bf(acc[7] * inv) << 16) | f2bf(acc[6] * inv);
        *(uint4*)&mean_bf[(size_t)n * HID + c * 8] = p;
    }
}

// ---------- SAGE layer: [N x 256] @ [256 x 128] + bias + LN + ReLU, bf16 h in-place ----------
__global__ __launch_bounds__(256) void sage_mfma(
    unsigned short* __restrict__ hbf, const unsigned short* __restrict__ mean_bf,
    const unsigned short* __restrict__ WT,    // [128 out][256 k] bf16 (k<128: Wl, else Wr)
    const float* __restrict__ bl, const float* __restrict__ g,
    const float* __restrict__ bet, int N) {
    const int t = threadIdx.x, wave = t >> 6, lane = t & 63;
    const int ln15 = lane & 15, quad = lane >> 4;
    const int blkBase = blockIdx.x * 128;

    short8 af[2][8];
#pragma unroll
    for (int tt = 0; tt < 2; tt++) {
        int m = blkBase + tt * 64 + wave * 16 + ln15;
        int mc = m < N ? m : N - 1;
#pragma unroll
        for (int kt = 0; kt < 4; kt++)
            af[tt][kt] = *(const short8*)&mean_bf[(size_t)mc * HID + kt * 32 + quad * 8];
#pragma unroll
        for (int kt = 0; kt < 4; kt++)
            af[tt][4 + kt] = *(const short8*)&hbf[(size_t)mc * HID + kt * 32 + quad * 8];
    }

    floatx4 acc[2][8];
#pragma unroll
    for (int nt = 0; nt < 8; nt++) {
        floatx4 a0 = {0.f, 0.f, 0.f, 0.f}, a1 = {0.f, 0.f, 0.f, 0.f};
#pragma unroll
        for (int kt = 0; kt < 8; kt++) {
            short8 b = *(const short8*)&WT[(nt * 16 + ln15) * 256 + kt * 32 + quad * 8];
            a0 = __builtin_amdgcn_mfma_f32_16x16x32_bf16(af[0][kt], b, a0, 0, 0, 0);
            a1 = __builtin_amdgcn_mfma_f32_16x16x32_bf16(af[1][kt], b, a1, 0, 0, 0);
        }
        acc[0][nt] = a0; acc[1][nt] = a1;
    }

    float blv[8], gv[8], bv[8];
#pragma unroll
    for (int nt = 0; nt < 8; nt++) {
        int col = nt * 16 + ln15;
        blv[nt] = bl[col]; gv[nt] = g[col]; bv[nt] = bet[col];
    }

#pragma unroll
    for (int tt = 0; tt < 2; tt++) {
#pragma unroll
        for (int r = 0; r < 4; r++) {
            float s = 0.f;
#pragma unroll
            for (int nt = 0; nt < 8; nt++) s += acc[tt][nt][r] + blv[nt];
            s += __shfl_xor(s, 1); s += __shfl_xor(s, 2);
            s += __shfl_xor(s, 4); s += __shfl_xor(s, 8);
            float mu = s * (1.f / 128.f);
            float q = 0.f;
#pragma unroll
            for (int nt = 0; nt < 8; nt++) { float c = acc[tt][nt][r] + blv[nt] - mu; q += c * c; }
            q += __shfl_xor(q, 1); q += __shfl_xor(q, 2);
            q += __shfl_xor(q, 4); q += __shfl_xor(q, 8);
            float rstd = rsqrtf(q * (1.f / 128.f) + 1e-5f);
            int node = blkBase + tt * 64 + wave * 16 + quad * 4 + r;
#pragma unroll
            for (int nt = 0; nt < 8; nt++) {
                float y = fmaxf((acc[tt][nt][r] + blv[nt] - mu) * rstd * gv[nt] + bv[nt], 0.f);
                float yp = __shfl_xor(y, 1);
                if (node < N && !(ln15 & 1)) {
                    unsigned pack = ((unsigned)f2bf(yp) << 16) | f2bf(y);
                    *(unsigned*)&hbf[(size_t)node * HID + nt * 16 + ln15] = pack;
                }
            }
        }
    }
}

// ---------- merged weight prep ----------
__global__ void prep_weights(const float* __restrict__ W1, const float* __restrict__ W2,
                             const float* __restrict__ Wl, const float* __restrict__ Wr,
                             unsigned short* __restrict__ W1T, unsigned short* __restrict__ W2T,
                             unsigned short* __restrict__ WST) {
    int i = blockIdx.x * 256 + threadIdx.x;
    if (i < 128 * K1) {
        int n = i / K1, k = i - n * K1;
        W1T[i] = (k < 268) ? f2bf(W1[k * HID + n]) : (unsigned short)0;
        return;
    }
    int j = i - 128 * K1;
    if (j < 64 * HID) {
        int n = j >> 7, k = j & 127;
        W2T[j] = f2bf(W2[k * 64 + n]);
        return;
    }
    int m = j - 64 * HID;
    if (m < 3 * 128 * 256) {
        int l = m >> 15, rem = m & 32767, n = rem >> 8, k = rem & 255;
        float v = (k < 128) ? Wl[l * 16384 + k * 128 + n] : Wr[l * 16384 + (k - 128) * 128 + n];
        WST[m] = f2bf(v);
    }
}

// ---------- MFMA edge MLP: 256 edges/block, 4 M-tiles/wave ----------
__global__ __launch_bounds__(256, 2) void edge_mlp_mfma(
    const unsigned short* __restrict__ hbf,
    const int* __restrict__ src, const int* __restrict__ dst,
    const float* __restrict__ eattr,
    const unsigned short* __restrict__ W1T, const float* __restrict__ b1,
    const unsigned short* __restrict__ W2T, const float* __restrict__ b2,
    const float* __restrict__ W3, const float* __restrict__ b3,
    float* __restrict__ out, int E)
{
    const int t = threadIdx.x;
    const int eBase = blockIdx.x * ET;
    __shared__ __align__(16) char smem[ET * Z2S * 4];   // 70656 B: z1 bf16 [256][136] / z2 fp32 [256][69]
    unsigned short* sZ1 = (unsigned short*)smem;
    float* sZ2 = (float*)smem;
    __shared__ int s_idx[2 * ET];

    for (int i = t; i < 2 * ET; i += 256) {
        int eo = i & (ET - 1);
        int e = eBase + eo;
        int ce = e < E ? e : 0;
        s_idx[i] = (i < ET) ? src[ce] : dst[ce];
    }
    __syncthreads();

    const int wave = t >> 6, lane = t & 63;
    const int ln15 = lane & 15, quad = lane >> 4;

    short8 af[4][9];
#pragma unroll
    for (int tt = 0; tt < 4; tt++) {
        int eo = tt * 64 + wave * 16 + ln15;
        int rs = s_idx[eo], rd = s_idx[ET + eo];
#pragma unroll
        for (int kt = 0; kt < 4; kt++)
            af[tt][kt] = *(const short8*)&hbf[(size_t)rs * HID + kt * 32 + quad * 8];
#pragma unroll
        for (int kt = 0; kt < 4; kt++)
            af[tt][4 + kt] = *(const short8*)&hbf[(size_t)rd * HID + kt * 32 + quad * 8];
        short8 a = {0, 0, 0, 0, 0, 0, 0, 0};
        int e = eBase + eo;
        if (e < E) {
            const float* ep = eattr + (size_t)e * 12;
            if (quad == 0) {
                float4 p0 = *(const float4*)ep, p1 = *(const float4*)(ep + 4);
                a[0] = (short)f2bf(p0.x); a[1] = (short)f2bf(p0.y);
                a[2] = (short)f2bf(p0.z); a[3] = (short)f2bf(p0.w);
                a[4] = (short)f2bf(p1.x); a[5] = (short)f2bf(p1.y);
                a[6] = (short)f2bf(p1.z); a[7] = (short)f2bf(p1.w);
            } else if (quad == 1) {
                float4 p2 = *(const float4*)(ep + 8);
                a[0] = (short)f2bf(p2.x); a[1] = (short)f2bf(p2.y);
                a[2] = (short)f2bf(p2.z); a[3] = (short)f2bf(p2.w);
            }
        }
        af[tt][8] = a;
    }

    // layer 1: [256 x 288] -> [256 x 128]; each B-frag load feeds 4 independent MFMAs
#pragma unroll
    for (int nt = 0; nt < 8; nt++) {
        floatx4 a0 = {0.f, 0.f, 0.f, 0.f}, a1 = a0, a2 = a0, a3 = a0;
#pragma unroll
        for (int kt = 0; kt < 9; kt++) {
            short8 b = *(const short8*)&W1T[(nt * 16 + ln15) * K1 + kt * 32 + quad * 8];
            a0 = __builtin_amdgcn_mfma_f32_16x16x32_bf16(af[0][kt], b, a0, 0, 0, 0);
            a1 = __builtin_amdgcn_mfma_f32_16x16x32_bf16(af[1][kt], b, a1, 0, 0, 0);
            a2 = __builtin_amdgcn_mfma_f32_16x16x32_bf16(af[2][kt], b, a2, 0, 0, 0);
            a3 = __builtin_amdgcn_mfma_f32_16x16x32_bf16(af[3][kt], b, a3, 0, 0, 0);
        }
        float bias = b1[nt * 16 + ln15];
        floatx4 aa[4] = {a0, a1, a2, a3};
#pragma unroll
        for (int tt = 0; tt < 4; tt++) {
#pragma unroll
            for (int r = 0; r < 4; r++) {
                float y = fmaxf(aa[tt][r] + bias, 0.f);
                float yp = __shfl_xor(y, 1);
                if (!(ln15 & 1)) {
                    int row = tt * 64 + wave * 16 + quad * 4 + r;
                    unsigned pk = ((unsigned)f2bf(yp) << 16) | f2bf(y);
                    *(unsigned*)&sZ1[row * Z1S + nt * 16 + ln15] = pk;
                }
            }
        }
    }
    __syncthreads();

    short8 zf[4][4];
#pragma unroll
    for (int tt = 0; tt < 4; tt++)
#pragma unroll
        for (int kt = 0; kt < 4; kt++)
            zf[tt][kt] = *(const short8*)&sZ1[(tt * 64 + wave * 16 + ln15) * Z1S + kt * 32 + quad * 8];
    __syncthreads();    // zf loaded before z2 overlays z1

    // layer 2: [256 x 128] -> [256 x 64]
#pragma unroll
    for (int nt = 0; nt < 4; nt++) {
        floatx4 a0 = {0.f, 0.f, 0.f, 0.f}, a1 = a0, a2 = a0, a3 = a0;
#pragma unroll
        for (int kt = 0; kt < 4; kt++) {
            short8 b = *(const short8*)&W2T[(nt * 16 + ln15) * HID + kt * 32 + quad * 8];
            a0 = __builtin_amdgcn_mfma_f32_16x16x32_bf16(zf[0][kt], b, a0, 0, 0, 0);
            a1 = __builtin_amdgcn_mfma_f32_16x16x32_bf16(zf[1][kt], b, a1, 0, 0, 0);
            a2 = __builtin_amdgcn_mfma_f32_16x16x32_bf16(zf[2][kt], b, a2, 0, 0, 0);
            a3 = __builtin_amdgcn_mfma_f32_16x16x32_bf16(zf[3][kt], b, a3, 0, 0, 0);
        }
        float bias = b2[nt * 16 + ln15];
        floatx4 aa[4] = {a0, a1, a2, a3};
#pragma unroll
        for (int tt = 0; tt < 4; tt++) {
#pragma unroll
            for (int r = 0; r < 4; r++) {
                int row = tt * 64 + wave * 16 + quad * 4 + r;
                sZ2[row * Z2S + nt * 16 + ln15] = fmaxf(aa[tt][r] + bias, 0.f);
            }
        }
    }
    __syncthreads();

    // layer 3 + softplus (fp32), one thread per edge
    {
        int ee = eBase + t;
        if (ee < E) {
            float a3 = b3[0];
            const float* z2 = sZ2 + t * Z2S;
#pragma unroll
            for (int k = 0; k < 64; k++) a3 = fmaf(z2[k], W3[k], a3);
            out[ee] = fmaxf(a3, 0.f) + log1pf(expf(-fabsf(a3)));
        }
    }
}

extern "C" void kernel_launch(void* const* d_in, const int* in_sizes, int n_in,
                              void* d_out, int out_size, void* d_ws, size_t ws_size,
                              hipStream_t stream) {
    const float* x       = (const float*)d_in[0];
    const int*   ei      = (const int*)d_in[1];
    const float* eattr   = (const float*)d_in[2];
    const float* node_W  = (const float*)d_in[3];
    const float* node_b  = (const float*)d_in[4];
    const float* sage_Wl = (const float*)d_in[5];
    const float* sage_bl = (const float*)d_in[6];
    const float* sage_Wr = (const float*)d_in[7];
    const float* ln_g    = (const float*)d_in[8];
    const float* ln_b    = (const float*)d_in[9];
    const float* W1 = (const float*)d_in[10];
    const float* b1 = (const float*)d_in[11];
    const float* W2 = (const float*)d_in[12];
    const float* b2 = (const float*)d_in[13];
    const float* W3 = (const float*)d_in[14];
    const float* b3 = (const float*)d_in[15];
    float* out = (float*)d_out;

    const int N = in_sizes[0] / 5;
    const int E = in_sizes[1] / 2;
    const int* src  = ei;
    const int* dstp = ei + E;

    char* ws = (char*)d_ws;
    size_t cur_off = 0;
    auto alloc = [&](size_t bytes) { size_t p = cur_off; cur_off = (cur_off + bytes + 255) & ~(size_t)255; return p; };
    unsigned short* hbf    = (unsigned short*)(ws + alloc((size_t)N * HID * 2));
    unsigned short* meanbf = (unsigned short*)(ws + alloc((size_t)N * HID * 2));
    int*            csr    = (int*)(ws + alloc((size_t)E * 4));
    unsigned*       degu   = (unsigned*)(ws + alloc((size_t)N * 4));
    unsigned*       curp   = (unsigned*)(ws + alloc((size_t)N * 4));
    unsigned*       offs   = (unsigned*)(ws + alloc((size_t)N * 4));
    unsigned*       bsum   = (unsigned*)(ws + alloc(64 * 4));
    unsigned short* W1T    = (unsigned short*)(ws + alloc(128 * K1 * 2));
    unsigned short* W2T    = (unsigned short*)(ws + alloc(64 * HID * 2));
    unsigned short* WST    = (unsigned short*)(ws + alloc(3 * 128 * 256 * 2));

    hipMemsetAsync(degu, 0, (size_t)N * sizeof(unsigned), stream);
    hipMemsetAsync(curp, 0, (size_t)N * sizeof(unsigned), stream);
    hist_kernel<<<(E + 255) / 256, 256, 0, stream>>>(dstp, degu, E);
    int NB = (N + 2047) / 2048;   // 49 for N=100000, fits the 64-lane bsum scan
    scan_partial<<<NB, 256, 0, stream>>>(degu, offs, bsum, N);
    scan_bsum<<<1, 64, 0, stream>>>(bsum, NB);
    scan_add<<<(N + 255) / 256, 256, 0, stream>>>(offs, bsum, N);
    csr_fill<<<(E + 255) / 256, 256, 0, stream>>>(src, dstp, offs, curp, csr, E);

    int prepTotal = 128 * K1 + 64 * HID + 3 * 128 * 256;
    prep_weights<<<(prepTotal + 255) / 256, 256, 0, stream>>>(W1, W2, sage_Wl, sage_Wr, W1T, W2T, WST);

    node_proj_kernel<<<(N * 64 + 255) / 256, 256, 0, stream>>>(x, node_W, node_b, hbf, N);

    for (int l = 0; l < 3; l++) {
        agg_csr<<<(N + 15) / 16, 256, 0, stream>>>(hbf, csr, offs, degu, meanbf, N);
        sage_mfma<<<(N + 127) / 128, 256, 0, stream>>>(
            hbf, meanbf, WST + (size_t)l * 128 * 256,
            sage_bl + (size_t)l * HID, ln_g + (size_t)l * HID, ln_b + (size_t)l * HID, N);
    }

    edge_mlp_mfma<<<(E + ET - 1) / ET, 256, 0, stream>>>(
        hbf, src, dstp, eattr, W1T, b1, W2T, b2, W3, b3, out, E);
}

// Round 6
// 689.813 us; speedup vs baseline: 5.3043x; 1.0129x over previous
//
#include <hip/hip_runtime.h>
#include <math.h>

#define HID 128
#define ET  128         // edges per block (edge MLP), 2 M-tiles per wave (R4 config)
#define K1  288         // padded K for layer 1 (268 -> 9*32)
#define Z1S 136         // z1 LDS stride in bf16
#define Z2S 69          // z2 LDS stride in fp32

typedef __attribute__((ext_vector_type(8))) short short8;   // 8 bf16 = 4 VGPRs
typedef __attribute__((ext_vector_type(4))) float floatx4;  // MFMA accumulator

static __device__ __forceinline__ unsigned short f2bf(float v) {
    unsigned u = __float_as_uint(v);
    u += 0x7fffu + ((u >> 16) & 1u);   // round-to-nearest-even
    return (unsigned short)(u >> 16);
}
static __device__ __forceinline__ float bf2f_lo(unsigned u) { return __uint_as_float(u << 16); }
static __device__ __forceinline__ float bf2f_hi(unsigned u) { return __uint_as_float(u & 0xffff0000u); }

// ---------- CSR build ----------
__global__ void hist_kernel(const int* __restrict__ dst, unsigned* __restrict__ deg, int E) {
    int e = blockIdx.x * 256 + threadIdx.x;
    if (e < E) atomicAdd(&deg[dst[e]], 1u);
}

__global__ __launch_bounds__(256) void scan_partial(const unsigned* __restrict__ deg,
        unsigned* __restrict__ off, unsigned* __restrict__ bsum, int N) {
    int t = threadIdx.x;
    int base = blockIdx.x * 2048 + t * 8;
    unsigned v[8]; unsigned run = 0;
#pragma unroll
    for (int i = 0; i < 8; i++) {
        int g = base + i;
        unsigned d = (g < N) ? deg[g] : 0u;
        v[i] = run; run += d;
    }
    __shared__ unsigned s[256];
    s[t] = run; __syncthreads();
    for (int o2 = 1; o2 < 256; o2 <<= 1) {
        unsigned x = (t >= o2) ? s[t - o2] : 0u;
        __syncthreads();
        s[t] += x;
        __syncthreads();
    }
    unsigned texcl = (t > 0) ? s[t - 1] : 0u;
    if (t == 255) bsum[blockIdx.x] = s[255];
#pragma unroll
    for (int i = 0; i < 8; i++) {
        int g = base + i;
        if (g < N) off[g] = texcl + v[i];
    }
}

__global__ void scan_bsum(unsigned* bsum, int B) {   // B <= 64, single wave inclusive
    int t = threadIdx.x;
    unsigned v = (t < B) ? bsum[t] : 0u;
    for (int o = 1; o < 64; o <<= 1) {
        unsigned x = __shfl_up(v, o);
        if (t >= o) v += x;
    }
    if (t < B) bsum[t] = v;
}

__global__ void scan_add(unsigned* __restrict__ off, const unsigned* __restrict__ bsum, int N) {
    int g = blockIdx.x * 256 + threadIdx.x;
    if (g >= N) return;
    int blk = g >> 11;
    if (blk > 0) off[g] += bsum[blk - 1];
}

// fills: csrS[pos]=src, csrD[pos]=dst, csrE[pos]=edge id, rank[e]=pos
__global__ void csr_fill(const int* __restrict__ src, const int* __restrict__ dst,
                         const unsigned* __restrict__ off, unsigned* __restrict__ cur,
                         int* __restrict__ csrS, int* __restrict__ csrD,
                         int* __restrict__ csrE, int* __restrict__ rank, int E) {
    int e = blockIdx.x * 256 + threadIdx.x;
    if (e >= E) return;
    int d = dst[e];
    unsigned p = off[d] + atomicAdd(&cur[d], 1u);
    csrS[p] = src[e];
    csrD[p] = d;
    csrE[p] = e;
    rank[e] = (int)p;
}

// ---------- node projection (writes bf16 h) ----------
__global__ void node_proj_kernel(const float* __restrict__ x, const float* __restrict__ W,
                                 const float* __restrict__ b, unsigned short* __restrict__ hbf, int N) {
    int i = blockIdx.x * 256 + threadIdx.x;   // over N*64, 2 cols/thread
    if (i >= N * 64) return;
    int n = i >> 6, f2 = (i & 63) * 2;
    float a0 = b[f2], a1 = b[f2 + 1];
#pragma unroll
    for (int k = 0; k < 5; k++) {
        float xv = x[n * 5 + k];
        a0 = fmaf(xv, W[k * HID + f2], a0);
        a1 = fmaf(xv, W[k * HID + f2 + 1], a1);
    }
    unsigned pack = ((unsigned)f2bf(a1) << 16) | f2bf(a0);
    *(unsigned*)&hbf[(size_t)n * HID + f2] = pack;
}

// ---------- mean aggregation: 4 nodes per wave, 16 lanes x ushort8 per row ----------
__global__ __launch_bounds__(256) void agg_csr(const unsigned short* __restrict__ hbf,
        const int* __restrict__ csr, const unsigned* __restrict__ off,
        const unsigned* __restrict__ degu, unsigned short* __restrict__ mean_bf, int N) {
    const int wv = threadIdx.x >> 6, lane = threadIdx.x & 63;
    const int g = lane >> 4, c = lane & 15;
    const int n = (blockIdx.x * 4 + wv) * 4 + g;
    const int nc = n < N ? n : N - 1;
    const unsigned o = off[nc];
    const unsigned d = (n < N) ? degu[nc] : 0u;
    unsigned dmax = d;
    dmax = max(dmax, (unsigned)__shfl_xor((int)dmax, 16));
    dmax = max(dmax, (unsigned)__shfl_xor((int)dmax, 32));

    float acc[8] = {0.f, 0.f, 0.f, 0.f, 0.f, 0.f, 0.f, 0.f};
    for (unsigned i = 0; i < dmax; i += 4) {
        unsigned p0 = (i     < d) ? o + i     : 0u;
        unsigned p1 = (i + 1 < d) ? o + i + 1 : 0u;
        unsigned p2 = (i + 2 < d) ? o + i + 2 : 0u;
        unsigned p3 = (i + 3 < d) ? o + i + 3 : 0u;
        int s0 = csr[p0], s1 = csr[p1], s2 = csr[p2], s3 = csr[p3];
        uint4 v0 = *(const uint4*)&hbf[(size_t)s0 * HID + c * 8];
        uint4 v1 = *(const uint4*)&hbf[(size_t)s1 * HID + c * 8];
        uint4 v2 = *(const uint4*)&hbf[(size_t)s2 * HID + c * 8];
        uint4 v3 = *(const uint4*)&hbf[(size_t)s3 * HID + c * 8];
        if (i < d) {
            acc[0] += bf2f_lo(v0.x); acc[1] += bf2f_hi(v0.x);
            acc[2] += bf2f_lo(v0.y); acc[3] += bf2f_hi(v0.y);
            acc[4] += bf2f_lo(v0.z); acc[5] += bf2f_hi(v0.z);
            acc[6] += bf2f_lo(v0.w); acc[7] += bf2f_hi(v0.w);
        }
        if (i + 1 < d) {
            acc[0] += bf2f_lo(v1.x); acc[1] += bf2f_hi(v1.x);
            acc[2] += bf2f_lo(v1.y); acc[3] += bf2f_hi(v1.y);
            acc[4] += bf2f_lo(v1.z); acc[5] += bf2f_hi(v1.z);
            acc[6] += bf2f_lo(v1.w); acc[7] += bf2f_hi(v1.w);
        }
        if (i + 2 < d) {
            acc[0] += bf2f_lo(v2.x); acc[1] += bf2f_hi(v2.x);
            acc[2] += bf2f_lo(v2.y); acc[3] += bf2f_hi(v2.y);
            acc[4] += bf2f_lo(v2.z); acc[5] += bf2f_hi(v2.z);
            acc[6] += bf2f_lo(v2.w); acc[7] += bf2f_hi(v2.w);
        }
        if (i + 3 < d) {
            acc[0] += bf2f_lo(v3.x); acc[1] += bf2f_hi(v3.x);
            acc[2] += bf2f_lo(v3.y); acc[3] += bf2f_hi(v3.y);
            acc[4] += bf2f_lo(v3.z); acc[5] += bf2f_hi(v3.z);
            acc[6] += bf2f_lo(v3.w); acc[7] += bf2f_hi(v3.w);
        }
    }
    if (n < N) {
        float inv = d ? 1.f / (float)d : 0.f;
        uint4 p;
        p.x = ((unsigned)f2bf(acc[1] * inv) << 16) | f2bf(acc[0] * inv);
        p.y = ((unsigned)f2bf(acc[3] * inv) << 16) | f2bf(acc[2] * inv);
        p.z = ((unsigned)f2bf(acc[5] * inv) << 16) | f2bf(acc[4] * inv);
        p.w = ((unsigned)f2bf(acc[7] * inv) << 16) | f2bf(acc[6] * inv);
        *(uint4*)&mean_bf[(size_t)n * HID + c * 8] = p;
    }
}

// ---------- SAGE layer: [N x 256] @ [256 x 128] + bias + LN + ReLU, bf16 h in-place ----------
__global__ __launch_bounds__(256) void sage_mfma(
    unsigned short* __restrict__ hbf, const unsigned short* __restrict__ mean_bf,
    const unsigned short* __restrict__ WT,    // [128 out][256 k] bf16 (k<128: Wl, else Wr)
    const float* __restrict__ bl, const float* __restrict__ g,
    const float* __restrict__ bet, int N) {
    const int t = threadIdx.x, wave = t >> 6, lane = t & 63;
    const int ln15 = lane & 15, quad = lane >> 4;
    const int blkBase = blockIdx.x * 128;

    short8 af[2][8];
#pragma unroll
    for (int tt = 0; tt < 2; tt++) {
        int m = blkBase + tt * 64 + wave * 16 + ln15;
        int mc = m < N ? m : N - 1;
#pragma unroll
        for (int kt = 0; kt < 4; kt++)
            af[tt][kt] = *(const short8*)&mean_bf[(size_t)mc * HID + kt * 32 + quad * 8];
#pragma unroll
        for (int kt = 0; kt < 4; kt++)
            af[tt][4 + kt] = *(const short8*)&hbf[(size_t)mc * HID + kt * 32 + quad * 8];
    }

    floatx4 acc[2][8];
#pragma unroll
    for (int nt = 0; nt < 8; nt++) {
        floatx4 a0 = {0.f, 0.f, 0.f, 0.f}, a1 = {0.f, 0.f, 0.f, 0.f};
#pragma unroll
        for (int kt = 0; kt < 8; kt++) {
            short8 b = *(const short8*)&WT[(nt * 16 + ln15) * 256 + kt * 32 + quad * 8];
            a0 = __builtin_amdgcn_mfma_f32_16x16x32_bf16(af[0][kt], b, a0, 0, 0, 0);
            a1 = __builtin_amdgcn_mfma_f32_16x16x32_bf16(af[1][kt], b, a1, 0, 0, 0);
        }
        acc[0][nt] = a0; acc[1][nt] = a1;
    }

    float blv[8], gv[8], bv[8];
#pragma unroll
    for (int nt = 0; nt < 8; nt++) {
        int col = nt * 16 + ln15;
        blv[nt] = bl[col]; gv[nt] = g[col]; bv[nt] = bet[col];
    }

#pragma unroll
    for (int tt = 0; tt < 2; tt++) {
#pragma unroll
        for (int r = 0; r < 4; r++) {
            float s = 0.f;
#pragma unroll
            for (int nt = 0; nt < 8; nt++) s += acc[tt][nt][r] + blv[nt];
            s += __shfl_xor(s, 1); s += __shfl_xor(s, 2);
            s += __shfl_xor(s, 4); s += __shfl_xor(s, 8);
            float mu = s * (1.f / 128.f);
            float q = 0.f;
#pragma unroll
            for (int nt = 0; nt < 8; nt++) { float c = acc[tt][nt][r] + blv[nt] - mu; q += c * c; }
            q += __shfl_xor(q, 1); q += __shfl_xor(q, 2);
            q += __shfl_xor(q, 4); q += __shfl_xor(q, 8);
            float rstd = rsqrtf(q * (1.f / 128.f) + 1e-5f);
            int node = blkBase + tt * 64 + wave * 16 + quad * 4 + r;
#pragma unroll
            for (int nt = 0; nt < 8; nt++) {
                float y = fmaxf((acc[tt][nt][r] + blv[nt] - mu) * rstd * gv[nt] + bv[nt], 0.f);
                float yp = __shfl_xor(y, 1);
                if (node < N && !(ln15 & 1)) {
                    unsigned pack = ((unsigned)f2bf(yp) << 16) | f2bf(y);
                    *(unsigned*)&hbf[(size_t)node * HID + nt * 16 + ln15] = pack;
                }
            }
        }
    }
}

// ---------- merged weight prep ----------
__global__ void prep_weights(const float* __restrict__ W1, const float* __restrict__ W2,
                             const float* __restrict__ Wl, const float* __restrict__ Wr,
                             unsigned short* __restrict__ W1T, unsigned short* __restrict__ W2T,
                             unsigned short* __restrict__ WST) {
    int i = blockIdx.x * 256 + threadIdx.x;
    if (i < 128 * K1) {
        int n = i / K1, k = i - n * K1;
        W1T[i] = (k < 268) ? f2bf(W1[k * HID + n]) : (unsigned short)0;
        return;
    }
    int j = i - 128 * K1;
    if (j < 64 * HID) {
        int n = j >> 7, k = j & 127;
        W2T[j] = f2bf(W2[k * 64 + n]);
        return;
    }
    int m = j - 64 * HID;
    if (m < 3 * 128 * 256) {
        int l = m >> 15, rem = m & 32767, n = rem >> 8, k = rem & 255;
        float v = (k < 128) ? Wl[l * 16384 + k * 128 + n] : Wr[l * 16384 + (k - 128) * 128 + n];
        WST[m] = f2bf(v);
    }
}

// ---------- MFMA edge MLP in CSR (dst-sorted) order: 128 pos/block, 2 M-tiles/wave ----------
__global__ __launch_bounds__(256) void edge_mlp_mfma(
    const unsigned short* __restrict__ hbf,
    const int* __restrict__ csrS, const int* __restrict__ csrD, const int* __restrict__ csrE,
    const float* __restrict__ eattr,
    const unsigned short* __restrict__ W1T, const float* __restrict__ b1,
    const unsigned short* __restrict__ W2T, const float* __restrict__ b2,
    const float* __restrict__ W3, const float* __restrict__ b3,
    float* __restrict__ tmp, int E)
{
    const int t = threadIdx.x;
    const int eBase = blockIdx.x * ET;
    __shared__ __align__(16) char smem[ET * Z2S * 4];   // 35328 B: z1 bf16 [128][136] / z2 fp32 [128][69]
    unsigned short* sZ1 = (unsigned short*)smem;
    float* sZ2 = (float*)smem;

    const int wave = t >> 6, lane = t & 63;
    const int ln15 = lane & 15, quad = lane >> 4;

    short8 af[2][9];
#pragma unroll
    for (int tt = 0; tt < 2; tt++) {
        int pos = eBase + tt * 64 + wave * 16 + ln15;
        int pc = pos < E ? pos : E - 1;
        int rs = csrS[pc], rd = csrD[pc], re = csrE[pc];
#pragma unroll
        for (int kt = 0; kt < 4; kt++)
            af[tt][kt] = *(const short8*)&hbf[(size_t)rs * HID + kt * 32 + quad * 8];
#pragma unroll
        for (int kt = 0; kt < 4; kt++)
            af[tt][4 + kt] = *(const short8*)&hbf[(size_t)rd * HID + kt * 32 + quad * 8];
        short8 a = {0, 0, 0, 0, 0, 0, 0, 0};
        if (pos < E) {
            const float* ep = eattr + (size_t)re * 12;
            if (quad == 0) {
                float4 p0 = *(const float4*)ep, p1 = *(const float4*)(ep + 4);
                a[0] = (short)f2bf(p0.x); a[1] = (short)f2bf(p0.y);
                a[2] = (short)f2bf(p0.z); a[3] = (short)f2bf(p0.w);
                a[4] = (short)f2bf(p1.x); a[5] = (short)f2bf(p1.y);
                a[6] = (short)f2bf(p1.z); a[7] = (short)f2bf(p1.w);
            } else if (quad == 1) {
                float4 p2 = *(const float4*)(ep + 8);
                a[0] = (short)f2bf(p2.x); a[1] = (short)f2bf(p2.y);
                a[2] = (short)f2bf(p2.z); a[3] = (short)f2bf(p2.w);
            }
        }
        af[tt][8] = a;
    }

    // layer 1: [128 x 288] -> [128 x 128]; B-frag loaded once per (nt,kt), used by both tiles
#pragma unroll
    for (int nt = 0; nt < 8; nt++) {
        floatx4 a0 = {0.f, 0.f, 0.f, 0.f}, a1 = {0.f, 0.f, 0.f, 0.f};
#pragma unroll
        for (int kt = 0; kt < 9; kt++) {
            short8 b = *(const short8*)&W1T[(nt * 16 + ln15) * K1 + kt * 32 + quad * 8];
            a0 = __builtin_amdgcn_mfma_f32_16x16x32_bf16(af[0][kt], b, a0, 0, 0, 0);
            a1 = __builtin_amdgcn_mfma_f32_16x16x32_bf16(af[1][kt], b, a1, 0, 0, 0);
        }
        float bias = b1[nt * 16 + ln15];
#pragma unroll
        for (int r = 0; r < 4; r++) {
            float y0 = fmaxf(a0[r] + bias, 0.f);
            float y1 = fmaxf(a1[r] + bias, 0.f);
            float y0p = __shfl_xor(y0, 1);
            float y1p = __shfl_xor(y1, 1);
            if (!(ln15 & 1)) {
                int row0 = wave * 16 + quad * 4 + r;
                unsigned pk0 = ((unsigned)f2bf(y0p) << 16) | f2bf(y0);
                unsigned pk1 = ((unsigned)f2bf(y1p) << 16) | f2bf(y1);
                *(unsigned*)&sZ1[row0 * Z1S + nt * 16 + ln15] = pk0;
                *(unsigned*)&sZ1[(64 + row0) * Z1S + nt * 16 + ln15] = pk1;
            }
        }
    }
    __syncthreads();

    short8 zf[2][4];
#pragma unroll
    for (int tt = 0; tt < 2; tt++)
#pragma unroll
        for (int kt = 0; kt < 4; kt++)
            zf[tt][kt] = *(const short8*)&sZ1[(tt * 64 + wave * 16 + ln15) * Z1S + kt * 32 + quad * 8];
    __syncthreads();    // zf loaded before z2 overlays z1

    // layer 2: [128 x 128] -> [128 x 64]
#pragma unroll
    for (int nt = 0; nt < 4; nt++) {
        floatx4 a0 = {0.f, 0.f, 0.f, 0.f}, a1 = {0.f, 0.f, 0.f, 0.f};
#pragma unroll
        for (int kt = 0; kt < 4; kt++) {
            short8 b = *(const short8*)&W2T[(nt * 16 + ln15) * HID + kt * 32 + quad * 8];
            a0 = __builtin_amdgcn_mfma_f32_16x16x32_bf16(zf[0][kt], b, a0, 0, 0, 0);
            a1 = __builtin_amdgcn_mfma_f32_16x16x32_bf16(zf[1][kt], b, a1, 0, 0, 0);
        }
        float bias = b2[nt * 16 + ln15];
#pragma unroll
        for (int r = 0; r < 4; r++) {
            int row0 = wave * 16 + quad * 4 + r;
            sZ2[row0 * Z2S + nt * 16 + ln15] = fmaxf(a0[r] + bias, 0.f);
            sZ2[(64 + row0) * Z2S + nt * 16 + ln15] = fmaxf(a1[r] + bias, 0.f);
        }
    }
    __syncthreads();

    // layer 3 + softplus (fp32), one thread per position (write tmp in CSR order)
    {
        int pos = eBase + t;
        if (t < ET && pos < E) {
            float a3 = b3[0];
            const float* z2 = sZ2 + t * Z2S;
#pragma unroll
            for (int k = 0; k < 64; k++) a3 = fmaf(z2[k], W3[k], a3);
            tmp[pos] = fmaxf(a3, 0.f) + log1pf(expf(-fabsf(a3)));
        }
    }
}

// ---------- restore original edge order: out[e] = tmp[rank[e]] ----------
__global__ void remap_out(const float* __restrict__ tmp, const int* __restrict__ rank,
                          float* __restrict__ out, int E) {
    int e = blockIdx.x * 256 + threadIdx.x;
    if (e < E) out[e] = tmp[rank[e]];
}

extern "C" void kernel_launch(void* const* d_in, const int* in_sizes, int n_in,
                              void* d_out, int out_size, void* d_ws, size_t ws_size,
                              hipStream_t stream) {
    const float* x       = (const float*)d_in[0];
    const int*   ei      = (const int*)d_in[1];
    const float* eattr   = (const float*)d_in[2];
    const float* node_W  = (const float*)d_in[3];
    const float* node_b  = (const float*)d_in[4];
    const float* sage_Wl = (const float*)d_in[5];
    const float* sage_bl = (const float*)d_in[6];
    const float* sage_Wr = (const float*)d_in[7];
    const float* ln_g    = (const float*)d_in[8];
    const float* ln_b    = (const float*)d_in[9];
    const float* W1 = (const float*)d_in[10];
    const float* b1 = (const float*)d_in[11];
    const float* W2 = (const float*)d_in[12];
    const float* b2 = (const float*)d_in[13];
    const float* W3 = (const float*)d_in[14];
    const float* b3 = (const float*)d_in[15];
    float* out = (float*)d_out;

    const int N = in_sizes[0] / 5;
    const int E = in_sizes[1] / 2;
    const int* src  = ei;
    const int* dstp = ei + E;

    char* ws = (char*)d_ws;
    size_t cur_off = 0;
    auto alloc = [&](size_t bytes) { size_t p = cur_off; cur_off = (cur_off + bytes + 255) & ~(size_t)255; return p; };
    unsigned short* hbf    = (unsigned short*)(ws + alloc((size_t)N * HID * 2));
    unsigned short* meanbf = (unsigned short*)(ws + alloc((size_t)N * HID * 2));
    int*            csrS   = (int*)(ws + alloc((size_t)E * 4));
    int*            csrD   = (int*)(ws + alloc((size_t)E * 4));
    int*            csrE   = (int*)(ws + alloc((size_t)E * 4));
    int*            rank   = (int*)(ws + alloc((size_t)E * 4));
    float*          tmpo   = (float*)(ws + alloc((size_t)E * 4));
    unsigned*       degu   = (unsigned*)(ws + alloc((size_t)N * 4));
    unsigned*       curp   = (unsigned*)(ws + alloc((size_t)N * 4));
    unsigned*       offs   = (unsigned*)(ws + alloc((size_t)N * 4));
    unsigned*       bsum   = (unsigned*)(ws + alloc(64 * 4));
    unsigned short* W1T    = (unsigned short*)(ws + alloc(128 * K1 * 2));
    unsigned short* W2T    = (unsigned short*)(ws + alloc(64 * HID * 2));
    unsigned short* WST    = (unsigned short*)(ws + alloc(3 * 128 * 256 * 2));

    hipMemsetAsync(degu, 0, (size_t)N * sizeof(unsigned), stream);
    hipMemsetAsync(curp, 0, (size_t)N * sizeof(unsigned), stream);
    hist_kernel<<<(E + 255) / 256, 256, 0, stream>>>(dstp, degu, E);
    int NB = (N + 2047) / 2048;   // 49 for N=100000, fits the 64-lane bsum scan
    scan_partial<<<NB, 256, 0, stream>>>(degu, offs, bsum, N);
    scan_bsum<<<1, 64, 0, stream>>>(bsum, NB);
    scan_add<<<(N + 255) / 256, 256, 0, stream>>>(offs, bsum, N);
    csr_fill<<<(E + 255) / 256, 256, 0, stream>>>(src, dstp, offs, curp, csrS, csrD, csrE, rank, E);

    int prepTotal = 128 * K1 + 64 * HID + 3 * 128 * 256;
    prep_weights<<<(prepTotal + 255) / 256, 256, 0, stream>>>(W1, W2, sage_Wl, sage_Wr, W1T, W2T, WST);

    node_proj_kernel<<<(N * 64 + 255) / 256, 256, 0, stream>>>(x, node_W, node_b, hbf, N);

    for (int l = 0; l < 3; l++) {
        agg_csr<<<(N + 15) / 16, 256, 0, stream>>>(hbf, csrS, offs, degu, meanbf, N);
        sage_mfma<<<(N + 127) / 128, 256, 0, stream>>>(
            hbf, meanbf, WST + (size_t)l * 128 * 256,
            sage_bl + (size_t)l * HID, ln_g + (size_t)l * HID, ln_b + (size_t)l * HID, N);
    }

    edge_mlp_mfma<<<(E + ET - 1) / ET, 256, 0, stream>>>(
        hbf, csrS, csrD, csrE, eattr, W1T, b1, W2T, b2, W3, b3, tmpo, E);
    remap_out<<<(E + 255) / 256, 256, 0, stream>>>(tmpo, rank, out, E);
}